// Round 11
// baseline (185.521 us; speedup 1.0000x reference)
//
#include <hip/hip_runtime.h>
#include <hip/hip_bf16.h>

#define BB 2
#define NN 2048
#define II 768
#define CC 256
#define DD 64
#define MM (CC * DD)   // 16384 q-rows (worst case)

typedef __attribute__((ext_vector_type(8))) short short8;
typedef __attribute__((ext_vector_type(4))) float f32x4;

static constexpr float SCALE = 0.036084391824351615f; // 1/sqrt(768)

__device__ __forceinline__ unsigned short f2bf(float f) {
  union { float f; unsigned int u; } v; v.f = f;
  unsigned int u = v.u;
  unsigned int r = u + 0x7fffu + ((u >> 16) & 1u);
  return (unsigned short)(r >> 16);
}
__device__ __forceinline__ float bf2f(unsigned short h) {
  union { unsigned int u; float f; } v; v.u = ((unsigned int)h) << 16;
  return v.f;
}

union U8 { unsigned short us[8]; uint4 v; };
struct US4 { unsigned short x, y, z, w; };

#define GLOAD_LDS16(gp, lp)                                                    \
  __builtin_amdgcn_global_load_lds(                                            \
      (const __attribute__((address_space(1))) unsigned int*)(gp),             \
      (__attribute__((address_space(3))) unsigned int*)(lp), 16, 0, 0)

// ---------------------------------------------------------------------------
// Fused f32->bf16 conversion + valid-row scan (last block).  Mpad now
// rounded to 256 (8-phase attn tile).
// ---------------------------------------------------------------------------
__global__ __launch_bounds__(256)
void cvt_scan_kernel(const float* __restrict__ demb, const float* __restrict__ x,
                     const float* __restrict__ Wq, const float* __restrict__ Wk,
                     const float* __restrict__ Wv, const int* __restrict__ dmask,
                     unsigned short* __restrict__ Qb, unsigned short* __restrict__ xb,
                     unsigned short* __restrict__ Wqb, unsigned short* __restrict__ Wkb,
                     unsigned short* __restrict__ Wvb,
                     int* __restrict__ idx, int* __restrict__ cstart,
                     int* __restrict__ ccnt, int* __restrict__ meta)
{
  if (blockIdx.x == gridDim.x - 1) {
    const int c = threadIdx.x;
    int4 dmv[16];
    const int4* src = (const int4*)(dmask + c * 64);
    int cnt = 0;
    #pragma unroll
    for (int u = 0; u < 16; ++u) {
      dmv[u] = src[u];
      cnt += (dmv[u].x != 0) + (dmv[u].y != 0) + (dmv[u].z != 0) + (dmv[u].w != 0);
    }
    __shared__ int s[256];
    s[c] = cnt;
    __syncthreads();
    for (int off = 1; off < 256; off <<= 1) {
      int v = (c >= off) ? s[c - off] : 0;
      __syncthreads();
      s[c] += v;
      __syncthreads();
    }
    const int excl = s[c] - cnt;
    cstart[c] = excl;
    ccnt[c] = cnt;
    int j = excl;
    #pragma unroll
    for (int u = 0; u < 16; ++u) {
      if (dmv[u].x) idx[j++] = c * 64 + u * 4 + 0;
      if (dmv[u].y) idx[j++] = c * 64 + u * 4 + 1;
      if (dmv[u].z) idx[j++] = c * 64 + u * 4 + 2;
      if (dmv[u].w) idx[j++] = c * 64 + u * 4 + 3;
    }
    if (c == 255) {
      int mv = s[255];
      int mpad = (mv + 255) & ~255;          // 256-tile for 8-phase attn
      for (int t = mv; t < mpad; ++t) idx[t] = 0;  // pad -> row 0 (valid)
      meta[0] = mpad;
    }
  }
  const int NF_DEMB = 3145728;          // elems/4
  const int NF_X    = 786432;
  const int NF_W    = 147456;
  const int NF_TOT  = NF_DEMB + NF_X + 3 * NF_W;
  for (int i = blockIdx.x * 256 + threadIdx.x; i < NF_TOT; i += gridDim.x * 256) {
    const float* src; unsigned short* dst; int off;
    if (i < NF_DEMB) {
      if (dmask[i / 192] == 0) continue;   // 192 float4-groups per row
      src = demb; dst = Qb; off = i;
    }
    else if (i < NF_DEMB + NF_X) { src = x; dst = xb; off = i - NF_DEMB; }
    else if (i < NF_DEMB + NF_X + NF_W) { src = Wq; dst = Wqb; off = i - NF_DEMB - NF_X; }
    else if (i < NF_DEMB + NF_X + 2 * NF_W) { src = Wk; dst = Wkb; off = i - NF_DEMB - NF_X - NF_W; }
    else { src = Wv; dst = Wvb; off = i - NF_DEMB - NF_X - 2 * NF_W; }
    float4 v = *(const float4*)(src + (size_t)off * 4);
    US4 o; o.x = f2bf(v.x); o.y = f2bf(v.y); o.z = f2bf(v.z); o.w = f2bf(v.w);
    *(US4*)(dst + (size_t)off * 4) = o;
  }
}

// ---------------------------------------------------------------------------
// All three projections in ONE dispatch (unchanged, proven).
// ---------------------------------------------------------------------------
__global__ __launch_bounds__(256, 2)
void proj3(const unsigned short* __restrict__ Qb,
           const unsigned short* __restrict__ xb,
           const unsigned short* __restrict__ Wqb,
           const unsigned short* __restrict__ Wkb,
           const unsigned short* __restrict__ Wvb,
           unsigned short* __restrict__ Qp,
           unsigned short* __restrict__ Kp,
           unsigned short* __restrict__ Vt,
           const int* __restrict__ gidx, const int* __restrict__ meta)
{
  const int T = blockIdx.x;
  const int j0 = (T % 6) * 128;
  const int t = T / 6;
  const int mode = (t < 128) ? 0 : ((t < 160) ? 1 : 2);
  const int m0 = (mode == 0 ? t : (mode == 1 ? t - 128 : t - 160)) * 128;
  if (mode == 0 && m0 >= meta[0]) return;
  const unsigned short* A = (mode == 0) ? Qb : xb;
  const unsigned short* W = (mode == 0) ? Wqb : (mode == 1 ? Wkb : Wvb);

  const int tid = threadIdx.x;
  const int lane = tid & 63, wv = tid >> 6;
  const int lrow = lane & 15, khi = lane >> 4;
  const int wr = wv >> 1, wc = wv & 1;

  __shared__ __align__(16) unsigned short smem[128 * 128];
  unsigned short* a_lds = smem;
  unsigned short* b_lds = smem + 128 * 64;

  int rowsrc[4];
  #pragma unroll
  for (int u = 0; u < 4; ++u) {
    int row = m0 + ((u * 256 + tid) >> 3);
    rowsrc[u] = (mode == 0) ? gidx[row] : row;
  }

  f32x4 acc[4][4] = {};

  for (int kc = 0; kc < 12; ++kc) {
    const int k0 = kc * 64;
    __syncthreads();
    #pragma unroll
    for (int u = 0; u < 4; ++u) {
      int idx = u * 256 + tid;
      int row = idx >> 3, g = idx & 7;
      int sg = g ^ (row & 7);
      GLOAD_LDS16(A + (size_t)rowsrc[u] * II + k0 + sg * 8, &a_lds[idx * 8]);
      GLOAD_LDS16(W + (size_t)(j0 + row) * II + k0 + sg * 8, &b_lds[idx * 8]);
    }
    __syncthreads();
    #pragma unroll
    for (int s = 0; s < 2; ++s) {
      short8 af[4], bf[4];
      #pragma unroll
      for (int m = 0; m < 4; ++m) {
        int ar = wr * 64 + m * 16 + lrow;
        int g = s * 4 + khi;
        af[m] = *(const short8*)&a_lds[(ar * 8 + (g ^ (ar & 7))) * 8];
      }
      #pragma unroll
      for (int f = 0; f < 4; ++f) {
        int br = wc * 64 + f * 16 + lrow;
        int g = s * 4 + khi;
        bf[f] = *(const short8*)&b_lds[(br * 8 + (g ^ (br & 7))) * 8];
      }
      #pragma unroll
      for (int m = 0; m < 4; ++m)
        #pragma unroll
        for (int f = 0; f < 4; ++f)
          acc[m][f] = __builtin_amdgcn_mfma_f32_16x16x32_bf16(af[m], bf[f], acc[m][f], 0, 0, 0);
    }
  }

  if (mode != 2) {
    unsigned short* out = (mode == 0) ? Qp : Kp;
    __syncthreads();
    #pragma unroll
    for (int m = 0; m < 4; ++m)
      #pragma unroll
      for (int r = 0; r < 4; ++r) {
        const int row = wr * 64 + m * 16 + khi * 4 + r;
        const int s8 = (row & 7) << 3;
        #pragma unroll
        for (int f = 0; f < 4; ++f) {
          int col = wc * 64 + f * 16 + lrow;
          smem[row * 128 + (col ^ s8)] = f2bf(acc[m][f][r]);
        }
      }
    __syncthreads();
    #pragma unroll
    for (int u = 0; u < 8; ++u) {
      int idx = u * 256 + tid;
      int row = idx >> 4, q = idx & 15;
      int gcol = (q ^ (row & 7)) << 3;
      *(uint4*)(out + (size_t)(m0 + row) * II + j0 + gcol) =
          *(const uint4*)&smem[row * 128 + q * 8];
    }
  } else {
    #pragma unroll
    for (int m = 0; m < 4; ++m)
      #pragma unroll
      for (int f = 0; f < 4; ++f)
        #pragma unroll
        for (int r = 0; r < 4; ++r) {
          int row = m0 + wr * 64 + m * 16 + khi * 4 + r;
          int col = j0 + wc * 64 + f * 16 + lrow;
          int bb = row >> 11, n = row & (NN - 1);
          Vt[((size_t)bb * II + col) * NN + n] = f2bf(acc[m][f][r]);
        }
  }
}

// ---------------------------------------------------------------------------
// 8-PHASE attention score GEMM.  256x256 tile, 512 thr (8 waves = 2M x 4N),
// per-wave output 128x64.  LDS = ring of 4 K-half regions (A 256x32 +
// B 256x32 = 32KB each, 128KB total).  Phase = (K-half g, C-half ch):
// {ds_read frags | stage 1 unit 2-K-halves ahead | barrier | lgkmcnt(0) |
//  setprio(1) 16 MFMA setprio(0) | [vmcnt(4) end of ch1] | barrier}.
// vmcnt-then-barrier publishes landed loads to ALL waves (per-wave vmcnt
// alone is insufficient).  Epilogue reuses LDS as 256x256 P tile.
// ---------------------------------------------------------------------------
__global__ __launch_bounds__(512, 1)
void attn_gemm8(const unsigned short* __restrict__ Qp,
                const unsigned short* __restrict__ Kp,
                const int* __restrict__ amask, const int* __restrict__ meta,
                float* __restrict__ lpart_out,
                unsigned short* __restrict__ P_out)
{
  const int m0 = blockIdx.z * 256;
  if (m0 >= meta[0]) return;
  const int ny = blockIdx.x;           // 0..7
  const int n0 = ny * 256;
  const int b  = blockIdx.y;
  const int tid = threadIdx.x;         // 0..511
  const int lane = tid & 63, wv = tid >> 6;   // 8 waves
  const int lrow = lane & 15, khi = lane >> 4;
  const int wr = wv >> 2, wcn = wv & 3;       // 2M x 4N wave grid

  __shared__ __align__(16) unsigned short smem[65536];   // 128 KB

  const unsigned short* Kb = Kp + (size_t)b * NN * II;
  const unsigned short* Qm = Qp + (size_t)m0 * II;
  const unsigned short* Kn = Kb + (size_t)n0 * II;

  f32x4 acc[8][4] = {};

  // stage one unit: K-half g, mat 0=A(Q rows) 1=B(K rows).  16KB = 2 loads/thr.
  auto STAGE = [&](int g, int mat) {
    unsigned short* dst = &smem[(g & 3) * 16384 + mat * 8192];
    const unsigned short* sb = mat ? Kn : Qm;
    const int kb = g * 32;
    #pragma unroll
    for (int u = 0; u < 2; ++u) {
      int idx = u * 512 + tid;
      int row = idx >> 2, gp = idx & 3;
      int sg = gp ^ (row & 3);
      GLOAD_LDS16(sb + (size_t)row * II + kb + sg * 8, dst + idx * 8);
    }
  };

  // prologue: K-halves 0 and 1
  STAGE(0, 0); STAGE(0, 1); STAGE(1, 0); STAGE(1, 1);
  asm volatile("s_waitcnt vmcnt(4)" ::: "memory");   // own g=0 landed
  __builtin_amdgcn_sched_barrier(0);
  __builtin_amdgcn_s_barrier();                       // publish: all g=0 landed

  short8 bfr[4];
  #pragma unroll 1
  for (int g = 0; g < 24; ++g) {
    const unsigned short* regA = &smem[(g & 3) * 16384];
    const unsigned short* regB = regA + 8192;
    #pragma unroll
    for (int ch = 0; ch < 2; ++ch) {
      short8 afr[4];
      #pragma unroll
      for (int j = 0; j < 4; ++j) {
        int rowA = wr * 128 + (ch * 4 + j) * 16 + lrow;
        afr[j] = *(const short8*)&regA[(rowA * 4 + (khi ^ (rowA & 3))) * 8];
      }
      if (ch == 0) {
        #pragma unroll
        for (int nf = 0; nf < 4; ++nf) {
          int rowB = wcn * 64 + nf * 16 + lrow;
          bfr[nf] = *(const short8*)&regB[(rowB * 4 + (khi ^ (rowB & 3))) * 8];
        }
      }
      if (g + 2 < 24) STAGE(g + 2, ch);     // A-unit at ch0, B-unit at ch1
      __builtin_amdgcn_s_barrier();
      asm volatile("s_waitcnt lgkmcnt(0)" ::: "memory");
      __builtin_amdgcn_sched_barrier(0);
      __builtin_amdgcn_s_setprio(1);
      #pragma unroll
      for (int j = 0; j < 4; ++j)
        #pragma unroll
        for (int nf = 0; nf < 4; ++nf)
          acc[ch * 4 + j][nf] = __builtin_amdgcn_mfma_f32_16x16x32_bf16(
              afr[j], bfr[nf], acc[ch * 4 + j][nf], 0, 0, 0);
      __builtin_amdgcn_s_setprio(0);
      if (ch == 1) {
        // wait-then-barrier: next phase reads region g+1 written by ALL waves
        if (g < 22) {
          asm volatile("s_waitcnt vmcnt(4)" ::: "memory");
        } else if (g == 22) {
          asm volatile("s_waitcnt vmcnt(0)" ::: "memory");
        }
        __builtin_amdgcn_sched_barrier(0);
      }
      __builtin_amdgcn_s_barrier();
    }
  }

  // ---- epilogue: P tile + l partials ----
  float msk[4];
  #pragma unroll
  for (int nf = 0; nf < 4; ++nf)
    msk[nf] = (amask[b * NN + n0 + wcn * 64 + nf * 16 + lrow] != 0) ? 1.0f : 0.0f;

  float* lrow_out = lpart_out + (((size_t)(b * 32 + ny * 4 + wcn)) << 14) + m0;
  #pragma unroll
  for (int mf = 0; mf < 8; ++mf) {
    #pragma unroll
    for (int rr = 0; rr < 4; ++rr) {
      const int row = wr * 128 + mf * 16 + khi * 4 + rr;   // 0..255 local
      const int s8 = (row & 7) << 3;
      float rs = 0.0f;
      #pragma unroll
      for (int nf = 0; nf < 4; ++nf) {
        float pe = msk[nf] * __expf(acc[mf][nf][rr] * SCALE);
        rs += pe;
        int col = wcn * 64 + nf * 16 + lrow;
        smem[row * 256 + (((col >> 3) << 3) ^ s8) + (col & 7)] = f2bf(pe);
      }
      rs += __shfl_xor(rs, 1); rs += __shfl_xor(rs, 2);
      rs += __shfl_xor(rs, 4); rs += __shfl_xor(rs, 8);
      if (lrow == 0) lrow_out[row] = rs;     // one of 32 partials per row
    }
  }
  __syncthreads();
  unsigned short* Pb = P_out + (size_t)b * MM * NN;
  #pragma unroll
  for (int u = 0; u < 16; ++u) {
    int idx = u * 512 + tid;                 // 8192 uint4 slots
    int row = idx >> 5, q = idx & 31;
    int gcol = (q ^ (row & 7)) << 3;
    *(uint4*)(Pb + (size_t)(m0 + row) * NN + n0 + gcol) =
        *(const uint4*)&smem[row * 256 + q * 8];
  }
}

// ---------------------------------------------------------------------------
// pp[b,c,n] = (1/cnt_c) * sum_{r in class c} P[b][r][n] / l_r,
// l_r = sum of 32 partials.  Grid (CC, BB, 2).
// ---------------------------------------------------------------------------
__global__ __launch_bounds__(128)
void ppred_kernel(const unsigned short* __restrict__ P,
                  const float* __restrict__ lpart,
                  const int* __restrict__ cstart, const int* __restrict__ ccnt,
                  unsigned short* __restrict__ pp)
{
  const int c = blockIdx.x, b = blockIdx.y;
  const int nz = blockIdx.z * 1024;
  const int tid = threadIdx.x;
  const int cs = cstart[c], cnt = ccnt[c];
  __shared__ float wgt[64];
  if (tid < cnt) {
    float lv = 0.0f;
    #pragma unroll
    for (int nt = 0; nt < 32; ++nt)
      lv += lpart[(((size_t)(b * 32 + nt)) << 14) + cs + tid];
    wgt[tid] = 1.0f / lv;
  }
  __syncthreads();
  const float invd = 1.0f / (float)cnt;
  float acc[8] = {};
  const unsigned short* Pr = P + ((size_t)b * MM + cs) * NN + nz + tid * 8;
  #pragma unroll 4
  for (int d = 0; d < cnt; ++d) {
    U8 v; v.v = *(const uint4*)(Pr + (size_t)d * NN);
    float w = wgt[d];
    #pragma unroll
    for (int e = 0; e < 8; ++e) acc[e] += w * bf2f(v.us[e]);
  }
  U8 o;
  #pragma unroll
  for (int e = 0; e < 8; ++e) o.us[e] = f2bf(acc[e] * invd);
  *(uint4*)(pp + ((size_t)(b * CC + c)) * NN + nz + tid * 8) = o.v;
}

// ---------------------------------------------------------------------------
// PV GEMM, K-SPLIT x4 (unchanged, proven).
// ---------------------------------------------------------------------------
__global__ __launch_bounds__(256, 2)
void pv_gemm(const unsigned short* __restrict__ pp,
             const unsigned short* __restrict__ Vt,
             float* __restrict__ pooled)
{
  const int m0 = blockIdx.x * 64;
  const int j0 = blockIdx.y * 64;
  const int b  = m0 >> 8;
  const int z  = blockIdx.z;
  const int tid = threadIdx.x;
  const int lane = tid & 63, wv = tid >> 6;
  const int lrow = lane & 15, khi = lane >> 4;

  __shared__ __align__(16) unsigned short a_lds[64 * 128];
  __shared__ __align__(16) unsigned short b_lds[64 * 128];

  f32x4 acc[4] = {};

  for (int kc = z * 4; kc < z * 4 + 4; ++kc) {
    const int k0 = kc * 128;
    __syncthreads();
    #pragma unroll
    for (int u = 0; u < 4; ++u) {
      int idx = u * 256 + tid;
      int row = idx >> 4, g = idx & 15;
      int sg = g ^ (row & 7);
      GLOAD_LDS16(pp + (size_t)(m0 + row) * NN + k0 + sg * 8, &a_lds[idx * 8]);
      GLOAD_LDS16(Vt + ((size_t)b * II + j0 + row) * NN + k0 + sg * 8, &b_lds[idx * 8]);
    }
    __syncthreads();
    #pragma unroll
    for (int s = 0; s < 4; ++s) {
      int g = s * 4 + khi;
      int ar = 16 * wv + lrow;
      short8 af = *(const short8*)&a_lds[(ar * 16 + (g ^ (ar & 7))) * 8];
      #pragma unroll
      for (int f = 0; f < 4; ++f) {
        int br = f * 16 + lrow;
        short8 bfr = *(const short8*)&b_lds[(br * 16 + (g ^ (br & 7))) * 8];
        acc[f] = __builtin_amdgcn_mfma_f32_16x16x32_bf16(af, bfr, acc[f], 0, 0, 0);
      }
    }
  }
  float* out = pooled + (size_t)z * (BB * CC * II);
  #pragma unroll
  for (int f = 0; f < 4; ++f)
    #pragma unroll
    for (int r = 0; r < 4; ++r) {
      int row = m0 + 16 * wv + khi * 4 + r;
      int col = j0 + f * 16 + lrow;
      out[(size_t)row * II + col] = acc[f][r];
    }
}

// ---------------------------------------------------------------------------
// LayerNorm over i (summing 4 pv partials) + dot with Wo.
// ---------------------------------------------------------------------------
__global__ __launch_bounds__(256)
void ln_out_kernel(const float* __restrict__ pooled,
                   const float* __restrict__ g, const float* __restrict__ beta,
                   const float* __restrict__ Wo, const float* __restrict__ bo,
                   float* __restrict__ out)
{
  const int bc = blockIdx.x;
  const int tid = threadIdx.x;
  const int lane = tid & 63, wv = tid >> 6;
  const size_t PSZ = (size_t)BB * CC * II;
  const float* r0 = pooled + (size_t)bc * II;
  float x0 = r0[tid]       + r0[PSZ + tid]       + r0[2 * PSZ + tid]       + r0[3 * PSZ + tid];
  float x1 = r0[tid + 256] + r0[PSZ + tid + 256] + r0[2 * PSZ + tid + 256] + r0[3 * PSZ + tid + 256];
  float x2 = r0[tid + 512] + r0[PSZ + tid + 512] + r0[2 * PSZ + tid + 512] + r0[3 * PSZ + tid + 512];
  float s = x0 + x1 + x2;
  float sq = x0 * x0 + x1 * x1 + x2 * x2;
  #pragma unroll
  for (int m = 1; m < 64; m <<= 1) { s += __shfl_xor(s, m); sq += __shfl_xor(sq, m); }
  __shared__ float red[8];
  if (lane == 0) { red[wv] = s; red[4 + wv] = sq; }
  __syncthreads();
  s = red[0] + red[1] + red[2] + red[3];
  sq = red[4] + red[5] + red[6] + red[7];
  const float mu = s * (1.0f / 768.0f);
  const float var = sq * (1.0f / 768.0f) - mu * mu;
  const float rs = rsqrtf(var + 1e-5f);
  float dot = ((x0 - mu) * rs * g[tid] + beta[tid]) * Wo[tid]
            + ((x1 - mu) * rs * g[tid + 256] + beta[tid + 256]) * Wo[tid + 256]
            + ((x2 - mu) * rs * g[tid + 512] + beta[tid + 512]) * Wo[tid + 512];
  #pragma unroll
  for (int m = 1; m < 64; m <<= 1) dot += __shfl_xor(dot, m);
  __syncthreads();
  if (lane == 0) red[wv] = dot;
  __syncthreads();
  if (tid == 0) out[bc] = red[0] + red[1] + red[2] + red[3] + bo[0];
}

// ---------------------------------------------------------------------------
extern "C" void kernel_launch(void* const* d_in, const int* in_sizes, int n_in,
                              void* d_out, int out_size, void* d_ws, size_t ws_size,
                              hipStream_t stream) {
  const float* x     = (const float*)d_in[0];   // [B,N,I]
  const int*   amask = (const int*)d_in[1];     // [B,N]
  const float* demb  = (const float*)d_in[2];   // [C,D,I]
  const int*   dmask = (const int*)d_in[3];     // [C,D]
  const float* Wq    = (const float*)d_in[4];
  const float* Wk    = (const float*)d_in[5];
  const float* Wv    = (const float*)d_in[6];
  const float* Wo    = (const float*)d_in[7];   // [1,I]
  const float* bo    = (const float*)d_in[8];   // [1]
  const float* lng   = (const float*)d_in[9];
  const float* lnb   = (const float*)d_in[10];

  char* ws = (char*)d_ws;
  const size_t OFF_QB  = 0;                                   // 25.2 MB
  const size_t OFF_XB  = OFF_QB + (size_t)MM * II * 2;        // 6.3 MB
  const size_t OFF_WQB = OFF_XB + (size_t)BB * NN * II * 2;   // 1.2 MB
  const size_t OFF_WKB = OFF_WQB + (size_t)II * II * 2;
  const size_t OFF_WVB = OFF_WKB + (size_t)II * II * 2;
  const size_t OFF_P   = 0;                                   // 134.2 MB
  const size_t OFF_PL  = 0;                                   // 4 x 1.6 MB (dead P)
  const size_t OFF_QP = (size_t)BB * MM * NN * 2;             // 25.2 MB
  const size_t OFF_KP = OFF_QP + (size_t)MM * II * 2;         // 6.3 MB
  const size_t OFF_VT = OFF_KP + (size_t)BB * NN * II * 2;    // 6.3 MB
  const size_t OFF_LP = OFF_VT + (size_t)BB * II * NN * 2;    // 8.4 MB (32 partials)
  const size_t OFF_PP = OFF_LP + (size_t)BB * 32 * MM * 4;    // 2.1 MB
  const size_t OFF_IDX = OFF_PP + (size_t)BB * CC * NN * 2;   // 64 KB
  const size_t OFF_CS  = OFF_IDX + (size_t)MM * 4;            // 1 KB
  const size_t OFF_CNT = OFF_CS + (size_t)CC * 4;             // 1 KB
  const size_t OFF_MET = OFF_CNT + (size_t)CC * 4;            // 4 B

  unsigned short* Qb  = (unsigned short*)(ws + OFF_QB);
  unsigned short* xb  = (unsigned short*)(ws + OFF_XB);
  unsigned short* Wqb = (unsigned short*)(ws + OFF_WQB);
  unsigned short* Wkb = (unsigned short*)(ws + OFF_WKB);
  unsigned short* Wvb = (unsigned short*)(ws + OFF_WVB);
  unsigned short* P   = (unsigned short*)(ws + OFF_P);
  float* pooled = (float*)(ws + OFF_PL);
  unsigned short* Qp  = (unsigned short*)(ws + OFF_QP);
  unsigned short* Kp  = (unsigned short*)(ws + OFF_KP);
  unsigned short* Vt  = (unsigned short*)(ws + OFF_VT);
  float* lpart = (float*)(ws + OFF_LP);
  unsigned short* pp = (unsigned short*)(ws + OFF_PP);
  int* idx    = (int*)(ws + OFF_IDX);
  int* cstart = (int*)(ws + OFF_CS);
  int* ccnt   = (int*)(ws + OFF_CNT);
  int* meta   = (int*)(ws + OFF_MET);

  cvt_scan_kernel<<<2048, 256, 0, stream>>>(demb, x, Wq, Wk, Wv, dmask,
                                            Qb, xb, Wqb, Wkb, Wvb,
                                            idx, cstart, ccnt, meta);

  proj3<<<192 * 6, 256, 0, stream>>>(Qb, xb, Wqb, Wkb, Wvb, Qp, Kp, Vt, idx, meta);

  attn_gemm8<<<dim3(NN / 256, BB, MM / 256), 512, 0, stream>>>(
      Qp, Kp, amask, meta, lpart, P);
  ppred_kernel<<<dim3(CC, BB, 2), 128, 0, stream>>>(P, lpart, cstart, ccnt, pp);

  pv_gemm<<<dim3((BB * CC) / 64, II / 64, 4), 256, 0, stream>>>(pp, Vt, pooled);
  ln_out_kernel<<<BB * CC, 256, 0, stream>>>(pooled, lng, lnb, Wo, bo, (float*)d_out);
}

// Round 12
// 153.063 us; speedup vs baseline: 1.2121x; 1.2121x over previous
//
#include <hip/hip_runtime.h>
#include <hip/hip_bf16.h>

#define BB 2
#define NN 2048
#define II 768
#define CC 256
#define DD 64
#define MM (CC * DD)   // 16384 q-rows (worst case)

typedef __attribute__((ext_vector_type(8))) short short8;
typedef __attribute__((ext_vector_type(4))) float f32x4;

static constexpr float SCALE = 0.036084391824351615f; // 1/sqrt(768)

__device__ __forceinline__ unsigned short f2bf(float f) {
  union { float f; unsigned int u; } v; v.f = f;
  unsigned int u = v.u;
  unsigned int r = u + 0x7fffu + ((u >> 16) & 1u);
  return (unsigned short)(r >> 16);
}
__device__ __forceinline__ float bf2f(unsigned short h) {
  union { unsigned int u; float f; } v; v.u = ((unsigned int)h) << 16;
  return v.f;
}

union U8 { unsigned short us[8]; uint4 v; };
struct US4 { unsigned short x, y, z, w; };

#define GLOAD_LDS16(gp, lp)                                                    \
  __builtin_amdgcn_global_load_lds(                                            \
      (const __attribute__((address_space(1))) unsigned int*)(gp),             \
      (__attribute__((address_space(3))) unsigned int*)(lp), 16, 0, 0)

// ---------------------------------------------------------------------------
// Fused f32->bf16 conversion (all blocks, grid-stride) + valid-row scan
// (last block only).  demb rows with dmask==0 skipped entirely.
// ---------------------------------------------------------------------------
__global__ __launch_bounds__(256)
void cvt_scan_kernel(const float* __restrict__ demb, const float* __restrict__ x,
                     const float* __restrict__ Wq, const float* __restrict__ Wk,
                     const float* __restrict__ Wv, const int* __restrict__ dmask,
                     unsigned short* __restrict__ Qb, unsigned short* __restrict__ xb,
                     unsigned short* __restrict__ Wqb, unsigned short* __restrict__ Wkb,
                     unsigned short* __restrict__ Wvb,
                     int* __restrict__ idx, int* __restrict__ cstart,
                     int* __restrict__ ccnt, int* __restrict__ meta)
{
  if (blockIdx.x == gridDim.x - 1) {
    const int c = threadIdx.x;
    int4 dmv[16];
    const int4* src = (const int4*)(dmask + c * 64);
    int cnt = 0;
    #pragma unroll
    for (int u = 0; u < 16; ++u) {
      dmv[u] = src[u];
      cnt += (dmv[u].x != 0) + (dmv[u].y != 0) + (dmv[u].z != 0) + (dmv[u].w != 0);
    }
    __shared__ int s[256];
    s[c] = cnt;
    __syncthreads();
    for (int off = 1; off < 256; off <<= 1) {
      int v = (c >= off) ? s[c - off] : 0;
      __syncthreads();
      s[c] += v;
      __syncthreads();
    }
    const int excl = s[c] - cnt;
    cstart[c] = excl;
    ccnt[c] = cnt;
    int j = excl;
    #pragma unroll
    for (int u = 0; u < 16; ++u) {
      if (dmv[u].x) idx[j++] = c * 64 + u * 4 + 0;
      if (dmv[u].y) idx[j++] = c * 64 + u * 4 + 1;
      if (dmv[u].z) idx[j++] = c * 64 + u * 4 + 2;
      if (dmv[u].w) idx[j++] = c * 64 + u * 4 + 3;
    }
    if (c == 255) {
      int mv = s[255];
      int mpad = (mv + 127) & ~127;
      for (int t = mv; t < mpad; ++t) idx[t] = 0;  // pad -> row 0 (valid)
      meta[0] = mpad;
    }
  }
  const int NF_DEMB = 3145728;          // elems/4
  const int NF_X    = 786432;
  const int NF_W    = 147456;
  const int NF_TOT  = NF_DEMB + NF_X + 3 * NF_W;
  for (int i = blockIdx.x * 256 + threadIdx.x; i < NF_TOT; i += gridDim.x * 256) {
    const float* src; unsigned short* dst; int off;
    if (i < NF_DEMB) {
      if (dmask[i / 192] == 0) continue;   // 192 float4-groups per row
      src = demb; dst = Qb; off = i;
    }
    else if (i < NF_DEMB + NF_X) { src = x; dst = xb; off = i - NF_DEMB; }
    else if (i < NF_DEMB + NF_X + NF_W) { src = Wq; dst = Wqb; off = i - NF_DEMB - NF_X; }
    else if (i < NF_DEMB + NF_X + 2 * NF_W) { src = Wk; dst = Wkb; off = i - NF_DEMB - NF_X - NF_W; }
    else { src = Wv; dst = Wvb; off = i - NF_DEMB - NF_X - 2 * NF_W; }
    float4 v = *(const float4*)(src + (size_t)off * 4);
    US4 o; o.x = f2bf(v.x); o.y = f2bf(v.y); o.z = f2bf(v.z); o.w = f2bf(v.w);
    *(US4*)(dst + (size_t)off * 4) = o;
  }
}

// ---------------------------------------------------------------------------
// All three projections in ONE dispatch (j-panel = T%6; t=T/6 selects
// Q(gathered, ghost-exit) / K / V).  128x128, BK=64, 4 waves,
// global_load_lds w16, XOR-swizzled source.
// ---------------------------------------------------------------------------
__global__ __launch_bounds__(256, 2)
void proj3(const unsigned short* __restrict__ Qb,
           const unsigned short* __restrict__ xb,
           const unsigned short* __restrict__ Wqb,
           const unsigned short* __restrict__ Wkb,
           const unsigned short* __restrict__ Wvb,
           unsigned short* __restrict__ Qp,
           unsigned short* __restrict__ Kp,
           unsigned short* __restrict__ Vt,
           const int* __restrict__ gidx, const int* __restrict__ meta)
{
  const int T = blockIdx.x;
  const int j0 = (T % 6) * 128;
  const int t = T / 6;
  const int mode = (t < 128) ? 0 : ((t < 160) ? 1 : 2);
  const int m0 = (mode == 0 ? t : (mode == 1 ? t - 128 : t - 160)) * 128;
  if (mode == 0 && m0 >= meta[0]) return;
  const unsigned short* A = (mode == 0) ? Qb : xb;
  const unsigned short* W = (mode == 0) ? Wqb : (mode == 1 ? Wkb : Wvb);

  const int tid = threadIdx.x;
  const int lane = tid & 63, wv = tid >> 6;
  const int lrow = lane & 15, khi = lane >> 4;
  const int wr = wv >> 1, wc = wv & 1;

  __shared__ __align__(16) unsigned short smem[128 * 128];
  unsigned short* a_lds = smem;
  unsigned short* b_lds = smem + 128 * 64;

  int rowsrc[4];
  #pragma unroll
  for (int u = 0; u < 4; ++u) {
    int row = m0 + ((u * 256 + tid) >> 3);
    rowsrc[u] = (mode == 0) ? gidx[row] : row;
  }

  f32x4 acc[4][4] = {};

  for (int kc = 0; kc < 12; ++kc) {
    const int k0 = kc * 64;
    __syncthreads();
    #pragma unroll
    for (int u = 0; u < 4; ++u) {
      int idx = u * 256 + tid;
      int row = idx >> 3, g = idx & 7;
      int sg = g ^ (row & 7);
      GLOAD_LDS16(A + (size_t)rowsrc[u] * II + k0 + sg * 8, &a_lds[idx * 8]);
      GLOAD_LDS16(W + (size_t)(j0 + row) * II + k0 + sg * 8, &b_lds[idx * 8]);
    }
    __syncthreads();
    #pragma unroll
    for (int s = 0; s < 2; ++s) {
      short8 af[4], bf[4];
      #pragma unroll
      for (int m = 0; m < 4; ++m) {
        int ar = wr * 64 + m * 16 + lrow;
        int g = s * 4 + khi;
        af[m] = *(const short8*)&a_lds[(ar * 8 + (g ^ (ar & 7))) * 8];
      }
      #pragma unroll
      for (int f = 0; f < 4; ++f) {
        int br = wc * 64 + f * 16 + lrow;
        int g = s * 4 + khi;
        bf[f] = *(const short8*)&b_lds[(br * 8 + (g ^ (br & 7))) * 8];
      }
      #pragma unroll
      for (int m = 0; m < 4; ++m)
        #pragma unroll
        for (int f = 0; f < 4; ++f)
          acc[m][f] = __builtin_amdgcn_mfma_f32_16x16x32_bf16(af[m], bf[f], acc[m][f], 0, 0, 0);
    }
  }

  if (mode != 2) {
    unsigned short* out = (mode == 0) ? Qp : Kp;
    __syncthreads();   // repurpose smem as 128x128 bf16 C tile
    #pragma unroll
    for (int m = 0; m < 4; ++m)
      #pragma unroll
      for (int r = 0; r < 4; ++r) {
        const int row = wr * 64 + m * 16 + khi * 4 + r;
        const int s8 = (row & 7) << 3;
        #pragma unroll
        for (int f = 0; f < 4; ++f) {
          int col = wc * 64 + f * 16 + lrow;
          smem[row * 128 + (col ^ s8)] = f2bf(acc[m][f][r]);
        }
      }
    __syncthreads();
    #pragma unroll
    for (int u = 0; u < 8; ++u) {
      int idx = u * 256 + tid;
      int row = idx >> 4, q = idx & 15;
      int gcol = (q ^ (row & 7)) << 3;
      *(uint4*)(out + (size_t)(m0 + row) * II + j0 + gcol) =
          *(const uint4*)&smem[row * 128 + q * 8];
    }
  } else {
    #pragma unroll
    for (int m = 0; m < 4; ++m)
      #pragma unroll
      for (int f = 0; f < 4; ++f)
        #pragma unroll
        for (int r = 0; r < 4; ++r) {
          int row = m0 + wr * 64 + m * 16 + khi * 4 + r;
          int col = j0 + wc * 64 + f * 16 + lrow;
          int bb = row >> 11, n = row & (NN - 1);
          Vt[((size_t)bb * II + col) * NN + n] = f2bf(acc[m][f][r]);
        }
  }
}

// ---------------------------------------------------------------------------
// Attention score GEMM over COMPACT rows (proven round-8/10 structure:
// 74us / MfmaUtil 30% / 0 bank conflicts).  Grid (x=ny, y=b, z=mx).
// 128x128, BK=64, 4 waves, global_load_lds w16, XOR-swizzled.
// Epilogue: P = amask*exp(S*scale) -> bf16 (LDS-staged, coalesced store);
// per-row partials -> l_part[b][ny][r] via red_lds combine.
// ---------------------------------------------------------------------------
__global__ __launch_bounds__(256, 4)
void attn_gemm1(const unsigned short* __restrict__ Qp,
                const unsigned short* __restrict__ Kp,
                const int* __restrict__ amask, const int* __restrict__ meta,
                float* __restrict__ lpart_out,
                unsigned short* __restrict__ P_out)
{
  const int m0 = blockIdx.z * 128;
  if (m0 >= meta[0]) return;
  const int ny = blockIdx.x;
  const int n0 = ny * 128;
  const int b  = blockIdx.y;
  const int tid = threadIdx.x;
  const int lane = tid & 63, wv = tid >> 6;
  const int lrow = lane & 15, khi = lane >> 4;
  const int wr = wv >> 1, wc = wv & 1;

  __shared__ __align__(16) unsigned short smem[128 * 128]; // a|b tiles, then P
  unsigned short* a_lds = smem;              // 128*64
  unsigned short* b_lds = smem + 128 * 64;   // 128*64
  __shared__ float red_lds[128 * 2];

  const unsigned short* Kb = Kp + (size_t)b * NN * II;

  f32x4 acc[4][4] = {};

  for (int kc = 0; kc < 12; ++kc) {
    const int k0 = kc * 64;
    __syncthreads();
    #pragma unroll
    for (int u = 0; u < 4; ++u) {
      int idx = u * 256 + tid;          // 1024 slots of 8 bf16 (16B)
      int row = idx >> 3, g = idx & 7;
      int sg = g ^ (row & 7);
      GLOAD_LDS16(Qp + (size_t)(m0 + row) * II + k0 + sg * 8, &a_lds[idx * 8]);
      GLOAD_LDS16(Kb + (size_t)(n0 + row) * II + k0 + sg * 8, &b_lds[idx * 8]);
    }
    __syncthreads();
    #pragma unroll
    for (int s = 0; s < 2; ++s) {
      short8 af[4], bf[4];
      #pragma unroll
      for (int m = 0; m < 4; ++m) {
        int ar = wr * 64 + m * 16 + lrow;
        int g = s * 4 + khi;
        af[m] = *(const short8*)&a_lds[(ar * 8 + (g ^ (ar & 7))) * 8];
      }
      #pragma unroll
      for (int f = 0; f < 4; ++f) {
        int br = wc * 64 + f * 16 + lrow;
        int g = s * 4 + khi;
        bf[f] = *(const short8*)&b_lds[(br * 8 + (g ^ (br & 7))) * 8];
      }
      #pragma unroll
      for (int m = 0; m < 4; ++m)
        #pragma unroll
        for (int f = 0; f < 4; ++f)
          acc[m][f] = __builtin_amdgcn_mfma_f32_16x16x32_bf16(af[m], bf[f], acc[m][f], 0, 0, 0);
    }
  }

  float msk[4];
  #pragma unroll
  for (int f = 0; f < 4; ++f)
    msk[f] = (amask[b * NN + n0 + wc * 64 + f * 16 + lrow] != 0) ? 1.0f : 0.0f;

  __syncthreads();   // done with a_lds/b_lds; repurpose smem as P tile

  #pragma unroll
  for (int m = 0; m < 4; ++m) {
    #pragma unroll
    for (int r = 0; r < 4; ++r) {
      const int row = wr * 64 + m * 16 + khi * 4 + r;     // 0..127 local
      const int s8 = (row & 7) << 3;
      float rs = 0.0f;
      #pragma unroll
      for (int f = 0; f < 4; ++f) {
        float pe = msk[f] * __expf(acc[m][f][r] * SCALE);
        rs += pe;
        int col = wc * 64 + f * 16 + lrow;
        smem[row * 128 + (col ^ s8)] = f2bf(pe);
      }
      rs += __shfl_xor(rs, 1); rs += __shfl_xor(rs, 2);
      rs += __shfl_xor(rs, 4); rs += __shfl_xor(rs, 8);
      if (lrow == 0) red_lds[row * 2 + wc] = rs;
    }
  }
  __syncthreads();
  if (tid < 128)
    lpart_out[((size_t)(b * 16 + ny) << 14) + m0 + tid] =
        red_lds[tid * 2] + red_lds[tid * 2 + 1];
  unsigned short* Pb = P_out + (size_t)b * MM * NN;
  #pragma unroll
  for (int u = 0; u < 8; ++u) {
    int idx = u * 256 + tid;            // 2048 uint4 slots
    int row = idx >> 4, q = idx & 15;
    int gcol = (q ^ (row & 7)) << 3;
    *(uint4*)(Pb + (size_t)(m0 + row) * NN + n0 + gcol) =
        *(const uint4*)&smem[row * 128 + q * 8];
  }
}

// ---------------------------------------------------------------------------
// pp[b,c,n] = (1/cnt_c) * sum_{r in class c} P[b][r][n] / l_r,
// l_r = sum of 16 partials.  Grid (CC, BB, 2): z picks the n-half;
// 128 threads x 8 bf16 = 1024 cols.
// ---------------------------------------------------------------------------
__global__ __launch_bounds__(128)
void ppred_kernel(const unsigned short* __restrict__ P,
                  const float* __restrict__ lpart,
                  const int* __restrict__ cstart, const int* __restrict__ ccnt,
                  unsigned short* __restrict__ pp)
{
  const int c = blockIdx.x, b = blockIdx.y;
  const int nz = blockIdx.z * 1024;
  const int tid = threadIdx.x;
  const int cs = cstart[c], cnt = ccnt[c];
  __shared__ float wgt[64];
  if (tid < cnt) {
    float lv = 0.0f;
    #pragma unroll
    for (int nt = 0; nt < 16; ++nt)
      lv += lpart[(((size_t)(b * 16 + nt)) << 14) + cs + tid];
    wgt[tid] = 1.0f / lv;
  }
  __syncthreads();
  const float invd = 1.0f / (float)cnt;
  float acc[8] = {};
  const unsigned short* Pr = P + ((size_t)b * MM + cs) * NN + nz + tid * 8;
  #pragma unroll 4
  for (int d = 0; d < cnt; ++d) {
    U8 v; v.v = *(const uint4*)(Pr + (size_t)d * NN);
    float w = wgt[d];
    #pragma unroll
    for (int e = 0; e < 8; ++e) acc[e] += w * bf2f(v.us[e]);
  }
  U8 o;
  #pragma unroll
  for (int e = 0; e < 8; ++e) o.us[e] = f2bf(acc[e] * invd);
  *(uint4*)(pp + ((size_t)(b * CC + c)) * NN + nz + tid * 8) = o.v;
}

// ---------------------------------------------------------------------------
// PV GEMM, K-SPLIT x4: pooled_z[mc][j] = sum_{n in quarter z} pp*Vt
// 384 blocks; 4 f32 partial buffers (summed in ln_out).
// ---------------------------------------------------------------------------
__global__ __launch_bounds__(256, 2)
void pv_gemm(const unsigned short* __restrict__ pp,
             const unsigned short* __restrict__ Vt,
             float* __restrict__ pooled)
{
  const int m0 = blockIdx.x * 64;
  const int j0 = blockIdx.y * 64;
  const int b  = m0 >> 8;
  const int z  = blockIdx.z;
  const int tid = threadIdx.x;
  const int lane = tid & 63, wv = tid >> 6;
  const int lrow = lane & 15, khi = lane >> 4;

  __shared__ __align__(16) unsigned short a_lds[64 * 128];
  __shared__ __align__(16) unsigned short b_lds[64 * 128];

  f32x4 acc[4] = {};

  for (int kc = z * 4; kc < z * 4 + 4; ++kc) {
    const int k0 = kc * 128;
    __syncthreads();
    #pragma unroll
    for (int u = 0; u < 4; ++u) {
      int idx = u * 256 + tid;
      int row = idx >> 4, g = idx & 15;
      int sg = g ^ (row & 7);
      GLOAD_LDS16(pp + (size_t)(m0 + row) * NN + k0 + sg * 8, &a_lds[idx * 8]);
      GLOAD_LDS16(Vt + ((size_t)b * II + j0 + row) * NN + k0 + sg * 8, &b_lds[idx * 8]);
    }
    __syncthreads();
    #pragma unroll
    for (int s = 0; s < 4; ++s) {
      int g = s * 4 + khi;
      int ar = 16 * wv + lrow;
      short8 af = *(const short8*)&a_lds[(ar * 16 + (g ^ (ar & 7))) * 8];
      #pragma unroll
      for (int f = 0; f < 4; ++f) {
        int br = f * 16 + lrow;
        short8 bfr = *(const short8*)&b_lds[(br * 16 + (g ^ (br & 7))) * 8];
        acc[f] = __builtin_amdgcn_mfma_f32_16x16x32_bf16(af, bfr, acc[f], 0, 0, 0);
      }
    }
  }
  float* out = pooled + (size_t)z * (BB * CC * II);
  #pragma unroll
  for (int f = 0; f < 4; ++f)
    #pragma unroll
    for (int r = 0; r < 4; ++r) {
      int row = m0 + 16 * wv + khi * 4 + r;
      int col = j0 + f * 16 + lrow;
      out[(size_t)row * II + col] = acc[f][r];
    }
}

// ---------------------------------------------------------------------------
// LayerNorm over i (summing 4 pv partials) + dot with Wo.
// ---------------------------------------------------------------------------
__global__ __launch_bounds__(256)
void ln_out_kernel(const float* __restrict__ pooled,
                   const float* __restrict__ g, const float* __restrict__ beta,
                   const float* __restrict__ Wo, const float* __restrict__ bo,
                   float* __restrict__ out)
{
  const int bc = blockIdx.x;
  const int tid = threadIdx.x;
  const int lane = tid & 63, wv = tid >> 6;
  const size_t PSZ = (size_t)BB * CC * II;
  const float* r0 = pooled + (size_t)bc * II;
  float x0 = r0[tid]       + r0[PSZ + tid]       + r0[2 * PSZ + tid]       + r0[3 * PSZ + tid];
  float x1 = r0[tid + 256] + r0[PSZ + tid + 256] + r0[2 * PSZ + tid + 256] + r0[3 * PSZ + tid + 256];
  float x2 = r0[tid + 512] + r0[PSZ + tid + 512] + r0[2 * PSZ + tid + 512] + r0[3 * PSZ + tid + 512];
  float s = x0 + x1 + x2;
  float sq = x0 * x0 + x1 * x1 + x2 * x2;
  #pragma unroll
  for (int m = 1; m < 64; m <<= 1) { s += __shfl_xor(s, m); sq += __shfl_xor(sq, m); }
  __shared__ float red[8];
  if (lane == 0) { red[wv] = s; red[4 + wv] = sq; }
  __syncthreads();
  s = red[0] + red[1] + red[2] + red[3];
  sq = red[4] + red[5] + red[6] + red[7];
  const float mu = s * (1.0f / 768.0f);
  const float var = sq * (1.0f / 768.0f) - mu * mu;
  const float rs = rsqrtf(var + 1e-5f);
  float dot = ((x0 - mu) * rs * g[tid] + beta[tid]) * Wo[tid]
            + ((x1 - mu) * rs * g[tid + 256] + beta[tid + 256]) * Wo[tid + 256]
            + ((x2 - mu) * rs * g[tid + 512] + beta[tid + 512]) * Wo[tid + 512];
  #pragma unroll
  for (int m = 1; m < 64; m <<= 1) dot += __shfl_xor(dot, m);
  __syncthreads();
  if (lane == 0) red[wv] = dot;
  __syncthreads();
  if (tid == 0) out[bc] = red[0] + red[1] + red[2] + red[3] + bo[0];
}

// ---------------------------------------------------------------------------
extern "C" void kernel_launch(void* const* d_in, const int* in_sizes, int n_in,
                              void* d_out, int out_size, void* d_ws, size_t ws_size,
                              hipStream_t stream) {
  const float* x     = (const float*)d_in[0];   // [B,N,I]
  const int*   amask = (const int*)d_in[1];     // [B,N]
  const float* demb  = (const float*)d_in[2];   // [C,D,I]
  const int*   dmask = (const int*)d_in[3];     // [C,D]
  const float* Wq    = (const float*)d_in[4];
  const float* Wk    = (const float*)d_in[5];
  const float* Wv    = (const float*)d_in[6];
  const float* Wo    = (const float*)d_in[7];   // [1,I]
  const float* bo    = (const float*)d_in[8];   // [1]
  const float* lng   = (const float*)d_in[9];
  const float* lnb   = (const float*)d_in[10];

  char* ws = (char*)d_ws;
  // Region A (0 .. 134.2MB): conversion buffers -> P (attn) -> pv partials.
  const size_t OFF_QB  = 0;                                   // 25.2 MB
  const size_t OFF_XB  = OFF_QB + (size_t)MM * II * 2;        // 6.3 MB
  const size_t OFF_WQB = OFF_XB + (size_t)BB * NN * II * 2;   // 1.2 MB
  const size_t OFF_WKB = OFF_WQB + (size_t)II * II * 2;
  const size_t OFF_WVB = OFF_WKB + (size_t)II * II * 2;
  const size_t OFF_P   = 0;                                   // 134.2 MB
  const size_t OFF_PL  = 0;                                   // 4 x 1.6 MB (dead P)
  // Region B (after P):
  const size_t OFF_QP = (size_t)BB * MM * NN * 2;             // 25.2 MB
  const size_t OFF_KP = OFF_QP + (size_t)MM * II * 2;         // 6.3 MB
  const size_t OFF_VT = OFF_KP + (size_t)BB * NN * II * 2;    // 6.3 MB
  const size_t OFF_LP = OFF_VT + (size_t)BB * II * NN * 2;    // 4.2 MB (16 partials)
  const size_t OFF_PP = OFF_LP + (size_t)BB * 16 * MM * 4;    // 2.1 MB
  const size_t OFF_IDX = OFF_PP + (size_t)BB * CC * NN * 2;   // 64 KB
  const size_t OFF_CS  = OFF_IDX + (size_t)MM * 4;            // 1 KB
  const size_t OFF_CNT = OFF_CS + (size_t)CC * 4;             // 1 KB
  const size_t OFF_MET = OFF_CNT + (size_t)CC * 4;            // 4 B

  unsigned short* Qb  = (unsigned short*)(ws + OFF_QB);
  unsigned short* xb  = (unsigned short*)(ws + OFF_XB);
  unsigned short* Wqb = (unsigned short*)(ws + OFF_WQB);
  unsigned short* Wkb = (unsigned short*)(ws + OFF_WKB);
  unsigned short* Wvb = (unsigned short*)(ws + OFF_WVB);
  unsigned short* P   = (unsigned short*)(ws + OFF_P);
  float* pooled = (float*)(ws + OFF_PL);
  unsigned short* Qp  = (unsigned short*)(ws + OFF_QP);
  unsigned short* Kp  = (unsigned short*)(ws + OFF_KP);
  unsigned short* Vt  = (unsigned short*)(ws + OFF_VT);
  float* lpart = (float*)(ws + OFF_LP);
  unsigned short* pp = (unsigned short*)(ws + OFF_PP);
  int* idx    = (int*)(ws + OFF_IDX);
  int* cstart = (int*)(ws + OFF_CS);
  int* ccnt   = (int*)(ws + OFF_CNT);
  int* meta   = (int*)(ws + OFF_MET);

  cvt_scan_kernel<<<2048, 256, 0, stream>>>(demb, x, Wq, Wk, Wv, dmask,
                                            Qb, xb, Wqb, Wkb, Wvb,
                                            idx, cstart, ccnt, meta);

  proj3<<<192 * 6, 256, 0, stream>>>(Qb, xb, Wqb, Wkb, Wvb, Qp, Kp, Vt, idx, meta);

  attn_gemm1<<<dim3(NN / 128, BB, MM / 128), 256, 0, stream>>>(
      Qp, Kp, amask, meta, lpart, P);
  ppred_kernel<<<dim3(CC, BB, 2), 128, 0, stream>>>(P, lpart, cstart, ccnt, pp);

  pv_gemm<<<dim3((BB * CC) / 64, II / 64, 4), 256, 0, stream>>>(pp, Vt, pooled);
  ln_out_kernel<<<BB * CC, 256, 0, stream>>>(pooled, lng, lnb, Wo, bo, (float*)d_out);
}

// Round 13
// 148.624 us; speedup vs baseline: 1.2483x; 1.0299x over previous
//
#include <hip/hip_runtime.h>
#include <hip/hip_bf16.h>

#define BB 2
#define NN 2048
#define II 768
#define CC 256
#define DD 64
#define MM (CC * DD)   // 16384 q-rows (worst case)

typedef __attribute__((ext_vector_type(8))) short short8;
typedef __attribute__((ext_vector_type(4))) float f32x4;

static constexpr float SCALE = 0.036084391824351615f; // 1/sqrt(768)

__device__ __forceinline__ unsigned short f2bf(float f) {
  union { float f; unsigned int u; } v; v.f = f;
  unsigned int u = v.u;
  unsigned int r = u + 0x7fffu + ((u >> 16) & 1u);
  return (unsigned short)(r >> 16);
}
__device__ __forceinline__ float bf2f(unsigned short h) {
  union { unsigned int u; float f; } v; v.u = ((unsigned int)h) << 16;
  return v.f;
}

union U8 { unsigned short us[8]; uint4 v; };
struct US4 { unsigned short x, y, z, w; };

#define GLOAD_LDS16(gp, lp)                                                    \
  __builtin_amdgcn_global_load_lds(                                            \
      (const __attribute__((address_space(1))) unsigned int*)(gp),             \
      (__attribute__((address_space(3))) unsigned int*)(lp), 16, 0, 0)

// ---------------------------------------------------------------------------
// Fused f32->bf16 conversion (all blocks, grid-stride) + valid-row scan
// (last block only).  demb rows with dmask==0 skipped entirely.
// ---------------------------------------------------------------------------
__global__ __launch_bounds__(256)
void cvt_scan_kernel(const float* __restrict__ demb, const float* __restrict__ x,
                     const float* __restrict__ Wq, const float* __restrict__ Wk,
                     const float* __restrict__ Wv, const int* __restrict__ dmask,
                     unsigned short* __restrict__ Qb, unsigned short* __restrict__ xb,
                     unsigned short* __restrict__ Wqb, unsigned short* __restrict__ Wkb,
                     unsigned short* __restrict__ Wvb,
                     int* __restrict__ idx, int* __restrict__ cstart,
                     int* __restrict__ ccnt, int* __restrict__ meta)
{
  if (blockIdx.x == gridDim.x - 1) {
    const int c = threadIdx.x;
    int4 dmv[16];
    const int4* src = (const int4*)(dmask + c * 64);
    int cnt = 0;
    #pragma unroll
    for (int u = 0; u < 16; ++u) {
      dmv[u] = src[u];
      cnt += (dmv[u].x != 0) + (dmv[u].y != 0) + (dmv[u].z != 0) + (dmv[u].w != 0);
    }
    __shared__ int s[256];
    s[c] = cnt;
    __syncthreads();
    for (int off = 1; off < 256; off <<= 1) {
      int v = (c >= off) ? s[c - off] : 0;
      __syncthreads();
      s[c] += v;
      __syncthreads();
    }
    const int excl = s[c] - cnt;
    cstart[c] = excl;
    ccnt[c] = cnt;
    int j = excl;
    #pragma unroll
    for (int u = 0; u < 16; ++u) {
      if (dmv[u].x) idx[j++] = c * 64 + u * 4 + 0;
      if (dmv[u].y) idx[j++] = c * 64 + u * 4 + 1;
      if (dmv[u].z) idx[j++] = c * 64 + u * 4 + 2;
      if (dmv[u].w) idx[j++] = c * 64 + u * 4 + 3;
    }
    if (c == 255) {
      int mv = s[255];
      int mpad = (mv + 127) & ~127;
      for (int t = mv; t < mpad; ++t) idx[t] = 0;  // pad -> row 0 (valid)
      meta[0] = mpad;
    }
  }
  const int NF_DEMB = 3145728;          // elems/4
  const int NF_X    = 786432;
  const int NF_W    = 147456;
  const int NF_TOT  = NF_DEMB + NF_X + 3 * NF_W;
  for (int i = blockIdx.x * 256 + threadIdx.x; i < NF_TOT; i += gridDim.x * 256) {
    const float* src; unsigned short* dst; int off;
    if (i < NF_DEMB) {
      if (dmask[i / 192] == 0) continue;   // 192 float4-groups per row
      src = demb; dst = Qb; off = i;
    }
    else if (i < NF_DEMB + NF_X) { src = x; dst = xb; off = i - NF_DEMB; }
    else if (i < NF_DEMB + NF_X + NF_W) { src = Wq; dst = Wqb; off = i - NF_DEMB - NF_X; }
    else if (i < NF_DEMB + NF_X + 2 * NF_W) { src = Wk; dst = Wkb; off = i - NF_DEMB - NF_X - NF_W; }
    else { src = Wv; dst = Wvb; off = i - NF_DEMB - NF_X - 2 * NF_W; }
    float4 v = *(const float4*)(src + (size_t)off * 4);
    US4 o; o.x = f2bf(v.x); o.y = f2bf(v.y); o.z = f2bf(v.z); o.w = f2bf(v.w);
    *(US4*)(dst + (size_t)off * 4) = o;
  }
}

// ---------------------------------------------------------------------------
// All three projections in ONE dispatch (j-panel = T%6; t=T/6 selects
// Q(gathered, ghost-exit) / K / V).  128x128, BK=64, 4 waves,
// global_load_lds w16, XOR-swizzled source.
// ---------------------------------------------------------------------------
__global__ __launch_bounds__(256, 2)
void proj3(const unsigned short* __restrict__ Qb,
           const unsigned short* __restrict__ xb,
           const unsigned short* __restrict__ Wqb,
           const unsigned short* __restrict__ Wkb,
           const unsigned short* __restrict__ Wvb,
           unsigned short* __restrict__ Qp,
           unsigned short* __restrict__ Kp,
           unsigned short* __restrict__ Vt,
           const int* __restrict__ gidx, const int* __restrict__ meta)
{
  const int T = blockIdx.x;
  const int j0 = (T % 6) * 128;
  const int t = T / 6;
  const int mode = (t < 128) ? 0 : ((t < 160) ? 1 : 2);
  const int m0 = (mode == 0 ? t : (mode == 1 ? t - 128 : t - 160)) * 128;
  if (mode == 0 && m0 >= meta[0]) return;
  const unsigned short* A = (mode == 0) ? Qb : xb;
  const unsigned short* W = (mode == 0) ? Wqb : (mode == 1 ? Wkb : Wvb);

  const int tid = threadIdx.x;
  const int lane = tid & 63, wv = tid >> 6;
  const int lrow = lane & 15, khi = lane >> 4;
  const int wr = wv >> 1, wc = wv & 1;

  __shared__ __align__(16) unsigned short smem[128 * 128];
  unsigned short* a_lds = smem;
  unsigned short* b_lds = smem + 128 * 64;

  int rowsrc[4];
  #pragma unroll
  for (int u = 0; u < 4; ++u) {
    int row = m0 + ((u * 256 + tid) >> 3);
    rowsrc[u] = (mode == 0) ? gidx[row] : row;
  }

  f32x4 acc[4][4] = {};

  for (int kc = 0; kc < 12; ++kc) {
    const int k0 = kc * 64;
    __syncthreads();
    #pragma unroll
    for (int u = 0; u < 4; ++u) {
      int idx = u * 256 + tid;
      int row = idx >> 3, g = idx & 7;
      int sg = g ^ (row & 7);
      GLOAD_LDS16(A + (size_t)rowsrc[u] * II + k0 + sg * 8, &a_lds[idx * 8]);
      GLOAD_LDS16(W + (size_t)(j0 + row) * II + k0 + sg * 8, &b_lds[idx * 8]);
    }
    __syncthreads();
    #pragma unroll
    for (int s = 0; s < 2; ++s) {
      short8 af[4], bf[4];
      #pragma unroll
      for (int m = 0; m < 4; ++m) {
        int ar = wr * 64 + m * 16 + lrow;
        int g = s * 4 + khi;
        af[m] = *(const short8*)&a_lds[(ar * 8 + (g ^ (ar & 7))) * 8];
      }
      #pragma unroll
      for (int f = 0; f < 4; ++f) {
        int br = wc * 64 + f * 16 + lrow;
        int g = s * 4 + khi;
        bf[f] = *(const short8*)&b_lds[(br * 8 + (g ^ (br & 7))) * 8];
      }
      #pragma unroll
      for (int m = 0; m < 4; ++m)
        #pragma unroll
        for (int f = 0; f < 4; ++f)
          acc[m][f] = __builtin_amdgcn_mfma_f32_16x16x32_bf16(af[m], bf[f], acc[m][f], 0, 0, 0);
    }
  }

  if (mode != 2) {
    unsigned short* out = (mode == 0) ? Qp : Kp;
    __syncthreads();   // repurpose smem as 128x128 bf16 C tile
    #pragma unroll
    for (int m = 0; m < 4; ++m)
      #pragma unroll
      for (int r = 0; r < 4; ++r) {
        const int row = wr * 64 + m * 16 + khi * 4 + r;
        const int s8 = (row & 7) << 3;
        #pragma unroll
        for (int f = 0; f < 4; ++f) {
          int col = wc * 64 + f * 16 + lrow;
          smem[row * 128 + (col ^ s8)] = f2bf(acc[m][f][r]);
        }
      }
    __syncthreads();
    #pragma unroll
    for (int u = 0; u < 8; ++u) {
      int idx = u * 256 + tid;
      int row = idx >> 4, q = idx & 15;
      int gcol = (q ^ (row & 7)) << 3;
      *(uint4*)(out + (size_t)(m0 + row) * II + j0 + gcol) =
          *(const uint4*)&smem[row * 128 + q * 8];
    }
  } else {
    #pragma unroll
    for (int m = 0; m < 4; ++m)
      #pragma unroll
      for (int f = 0; f < 4; ++f)
        #pragma unroll
        for (int r = 0; r < 4; ++r) {
          int row = m0 + wr * 64 + m * 16 + khi * 4 + r;
          int col = j0 + wc * 64 + f * 16 + lrow;
          int bb = row >> 11, n = row & (NN - 1);
          Vt[((size_t)bb * II + col) * NN + n] = f2bf(acc[m][f][r]);
        }
  }
}

// ---------------------------------------------------------------------------
// Attention score GEMM over COMPACT rows (proven structure: 74us /
// MfmaUtil 30% / 0 bank conflicts).  Grid (x=ny, y=b, z=mx).
// 128x128, BK=64, 4 waves, global_load_lds w16, XOR-swizzled.
// Epilogue: P = amask*exp(S*scale) -> FP8 e4m3 (halves P traffic; values
// in [0,~50] well inside e4m3 range 448); LDS-staged coalesced store;
// per-row partials (f32, pre-rounding) -> l_part[b][ny][r] via red_lds.
// ---------------------------------------------------------------------------
__global__ __launch_bounds__(256, 4)
void attn_gemm1(const unsigned short* __restrict__ Qp,
                const unsigned short* __restrict__ Kp,
                const int* __restrict__ amask, const int* __restrict__ meta,
                float* __restrict__ lpart_out,
                unsigned char* __restrict__ P_out)
{
  const int m0 = blockIdx.z * 128;
  if (m0 >= meta[0]) return;
  const int ny = blockIdx.x;
  const int n0 = ny * 128;
  const int b  = blockIdx.y;
  const int tid = threadIdx.x;
  const int lane = tid & 63, wv = tid >> 6;
  const int lrow = lane & 15, khi = lane >> 4;
  const int wr = wv >> 1, wc = wv & 1;

  __shared__ __align__(16) unsigned short smem[128 * 128]; // a|b tiles, then P
  unsigned short* a_lds = smem;              // 128*64
  unsigned short* b_lds = smem + 128 * 64;   // 128*64
  __shared__ float red_lds[128 * 2];

  const unsigned short* Kb = Kp + (size_t)b * NN * II;

  f32x4 acc[4][4] = {};

  for (int kc = 0; kc < 12; ++kc) {
    const int k0 = kc * 64;
    __syncthreads();
    #pragma unroll
    for (int u = 0; u < 4; ++u) {
      int idx = u * 256 + tid;          // 1024 slots of 8 bf16 (16B)
      int row = idx >> 3, g = idx & 7;
      int sg = g ^ (row & 7);
      GLOAD_LDS16(Qp + (size_t)(m0 + row) * II + k0 + sg * 8, &a_lds[idx * 8]);
      GLOAD_LDS16(Kb + (size_t)(n0 + row) * II + k0 + sg * 8, &b_lds[idx * 8]);
    }
    __syncthreads();
    #pragma unroll
    for (int s = 0; s < 2; ++s) {
      short8 af[4], bf[4];
      #pragma unroll
      for (int m = 0; m < 4; ++m) {
        int ar = wr * 64 + m * 16 + lrow;
        int g = s * 4 + khi;
        af[m] = *(const short8*)&a_lds[(ar * 8 + (g ^ (ar & 7))) * 8];
      }
      #pragma unroll
      for (int f = 0; f < 4; ++f) {
        int br = wc * 64 + f * 16 + lrow;
        int g = s * 4 + khi;
        bf[f] = *(const short8*)&b_lds[(br * 8 + (g ^ (br & 7))) * 8];
      }
      #pragma unroll
      for (int m = 0; m < 4; ++m)
        #pragma unroll
        for (int f = 0; f < 4; ++f)
          acc[m][f] = __builtin_amdgcn_mfma_f32_16x16x32_bf16(af[m], bf[f], acc[m][f], 0, 0, 0);
    }
  }

  float msk[4];
  #pragma unroll
  for (int f = 0; f < 4; ++f)
    msk[f] = (amask[b * NN + n0 + wc * 64 + f * 16 + lrow] != 0) ? 1.0f : 0.0f;

  __syncthreads();   // done with a_lds/b_lds; repurpose smem as fp8 P tile

  unsigned char* smemB = (unsigned char*)smem;   // 128 x 128 bytes (16 KB)
  #pragma unroll
  for (int m = 0; m < 4; ++m) {
    #pragma unroll
    for (int r = 0; r < 4; ++r) {
      const int row = wr * 64 + m * 16 + khi * 4 + r;     // 0..127 local
      const int s8 = (row & 7) << 3;                       // 8-byte-group XOR
      float rs = 0.0f;
      #pragma unroll
      for (int f = 0; f < 4; ++f) {
        float pe = msk[f] * __expf(acc[m][f][r] * SCALE);
        rs += pe;
        int col = wc * 64 + f * 16 + lrow;                 // byte col 0..127
        smemB[row * 128 + (col ^ s8)] =
            (unsigned char)(__builtin_amdgcn_cvt_pk_fp8_f32(pe, pe, 0, 0) & 0xff);
      }
      rs += __shfl_xor(rs, 1); rs += __shfl_xor(rs, 2);
      rs += __shfl_xor(rs, 4); rs += __shfl_xor(rs, 8);
      if (lrow == 0) red_lds[row * 2 + wc] = rs;
    }
  }
  __syncthreads();
  if (tid < 128)
    lpart_out[((size_t)(b * 16 + ny) << 14) + m0 + tid] =
        red_lds[tid * 2] + red_lds[tid * 2 + 1];
  unsigned char* Pb = P_out + (size_t)b * MM * NN;
  #pragma unroll
  for (int u = 0; u < 8; ++u) {
    int idx = u * 256 + tid;            // 2048 uint2 slots (8 B each)
    int row = idx >> 4, q = idx & 15;
    int gcol = (q ^ (row & 7)) << 3;    // un-swizzled byte col group
    *(uint2*)(Pb + (size_t)(m0 + row) * NN + n0 + gcol) =
        *(const uint2*)&smemB[row * 128 + q * 8];
  }
}

// ---------------------------------------------------------------------------
// pp[b,c,n] = (1/cnt_c) * sum_{r in class c} P[b][r][n] / l_r  (P is fp8
// e4m3, HW-decoded).  l_r = sum of 16 partials.  Grid (CC, BB, 2).
// ---------------------------------------------------------------------------
__global__ __launch_bounds__(128)
void ppred_kernel(const unsigned char* __restrict__ P,
                  const float* __restrict__ lpart,
                  const int* __restrict__ cstart, const int* __restrict__ ccnt,
                  unsigned short* __restrict__ pp)
{
  const int c = blockIdx.x, b = blockIdx.y;
  const int nz = blockIdx.z * 1024;
  const int tid = threadIdx.x;
  const int cs = cstart[c], cnt = ccnt[c];
  __shared__ float wgt[64];
  if (tid < cnt) {
    float lv = 0.0f;
    #pragma unroll
    for (int nt = 0; nt < 16; ++nt)
      lv += lpart[(((size_t)(b * 16 + nt)) << 14) + cs + tid];
    wgt[tid] = 1.0f / lv;
  }
  __syncthreads();
  const float invd = 1.0f / (float)cnt;
  float acc[8] = {};
  const unsigned char* Pr = P + ((size_t)b * MM + cs) * NN + nz + tid * 8;
  #pragma unroll 4
  for (int d = 0; d < cnt; ++d) {
    uint2 v = *(const uint2*)(Pr + (size_t)d * NN);
    float w = wgt[d];
    acc[0] += w * __builtin_amdgcn_cvt_f32_fp8(v.x, 0);
    acc[1] += w * __builtin_amdgcn_cvt_f32_fp8(v.x, 1);
    acc[2] += w * __builtin_amdgcn_cvt_f32_fp8(v.x, 2);
    acc[3] += w * __builtin_amdgcn_cvt_f32_fp8(v.x, 3);
    acc[4] += w * __builtin_amdgcn_cvt_f32_fp8(v.y, 0);
    acc[5] += w * __builtin_amdgcn_cvt_f32_fp8(v.y, 1);
    acc[6] += w * __builtin_amdgcn_cvt_f32_fp8(v.y, 2);
    acc[7] += w * __builtin_amdgcn_cvt_f32_fp8(v.y, 3);
  }
  U8 o;
  #pragma unroll
  for (int e = 0; e < 8; ++e) o.us[e] = f2bf(acc[e] * invd);
  *(uint4*)(pp + ((size_t)(b * CC + c)) * NN + nz + tid * 8) = o.v;
}

// ---------------------------------------------------------------------------
// PV GEMM, K-SPLIT x4: pooled_z[mc][j] = sum_{n in quarter z} pp*Vt
// 384 blocks; 4 f32 partial buffers (summed in ln_out).
// ---------------------------------------------------------------------------
__global__ __launch_bounds__(256, 2)
void pv_gemm(const unsigned short* __restrict__ pp,
             const unsigned short* __restrict__ Vt,
             float* __restrict__ pooled)
{
  const int m0 = blockIdx.x * 64;
  const int j0 = blockIdx.y * 64;
  const int b  = m0 >> 8;
  const int z  = blockIdx.z;
  const int tid = threadIdx.x;
  const int lane = tid & 63, wv = tid >> 6;
  const int lrow = lane & 15, khi = lane >> 4;

  __shared__ __align__(16) unsigned short a_lds[64 * 128];
  __shared__ __align__(16) unsigned short b_lds[64 * 128];

  f32x4 acc[4] = {};

  for (int kc = z * 4; kc < z * 4 + 4; ++kc) {
    const int k0 = kc * 128;
    __syncthreads();
    #pragma unroll
    for (int u = 0; u < 4; ++u) {
      int idx = u * 256 + tid;
      int row = idx >> 4, g = idx & 15;
      int sg = g ^ (row & 7);
      GLOAD_LDS16(pp + (size_t)(m0 + row) * NN + k0 + sg * 8, &a_lds[idx * 8]);
      GLOAD_LDS16(Vt + ((size_t)b * II + j0 + row) * NN + k0 + sg * 8, &b_lds[idx * 8]);
    }
    __syncthreads();
    #pragma unroll
    for (int s = 0; s < 4; ++s) {
      int g = s * 4 + khi;
      int ar = 16 * wv + lrow;
      short8 af = *(const short8*)&a_lds[(ar * 16 + (g ^ (ar & 7))) * 8];
      #pragma unroll
      for (int f = 0; f < 4; ++f) {
        int br = f * 16 + lrow;
        short8 bfr = *(const short8*)&b_lds[(br * 16 + (g ^ (br & 7))) * 8];
        acc[f] = __builtin_amdgcn_mfma_f32_16x16x32_bf16(af, bfr, acc[f], 0, 0, 0);
      }
    }
  }
  float* out = pooled + (size_t)z * (BB * CC * II);
  #pragma unroll
  for (int f = 0; f < 4; ++f)
    #pragma unroll
    for (int r = 0; r < 4; ++r) {
      int row = m0 + 16 * wv + khi * 4 + r;
      int col = j0 + f * 16 + lrow;
      out[(size_t)row * II + col] = acc[f][r];
    }
}

// ---------------------------------------------------------------------------
// LayerNorm over i (summing 4 pv partials) + dot with Wo.
// ---------------------------------------------------------------------------
__global__ __launch_bounds__(256)
void ln_out_kernel(const float* __restrict__ pooled,
                   const float* __restrict__ g, const float* __restrict__ beta,
                   const float* __restrict__ Wo, const float* __restrict__ bo,
                   float* __restrict__ out)
{
  const int bc = blockIdx.x;
  const int tid = threadIdx.x;
  const int lane = tid & 63, wv = tid >> 6;
  const size_t PSZ = (size_t)BB * CC * II;
  const float* r0 = pooled + (size_t)bc * II;
  float x0 = r0[tid]       + r0[PSZ + tid]       + r0[2 * PSZ + tid]       + r0[3 * PSZ + tid];
  float x1 = r0[tid + 256] + r0[PSZ + tid + 256] + r0[2 * PSZ + tid + 256] + r0[3 * PSZ + tid + 256];
  float x2 = r0[tid + 512] + r0[PSZ + tid + 512] + r0[2 * PSZ + tid + 512] + r0[3 * PSZ + tid + 512];
  float s = x0 + x1 + x2;
  float sq = x0 * x0 + x1 * x1 + x2 * x2;
  #pragma unroll
  for (int m = 1; m < 64; m <<= 1) { s += __shfl_xor(s, m); sq += __shfl_xor(sq, m); }
  __shared__ float red[8];
  if (lane == 0) { red[wv] = s; red[4 + wv] = sq; }
  __syncthreads();
  s = red[0] + red[1] + red[2] + red[3];
  sq = red[4] + red[5] + red[6] + red[7];
  const float mu = s * (1.0f / 768.0f);
  const float var = sq * (1.0f / 768.0f) - mu * mu;
  const float rs = rsqrtf(var + 1e-5f);
  float dot = ((x0 - mu) * rs * g[tid] + beta[tid]) * Wo[tid]
            + ((x1 - mu) * rs * g[tid + 256] + beta[tid + 256]) * Wo[tid + 256]
            + ((x2 - mu) * rs * g[tid + 512] + beta[tid + 512]) * Wo[tid + 512];
  #pragma unroll
  for (int m = 1; m < 64; m <<= 1) dot += __shfl_xor(dot, m);
  __syncthreads();
  if (lane == 0) red[wv] = dot;
  __syncthreads();
  if (tid == 0) out[bc] = red[0] + red[1] + red[2] + red[3] + bo[0];
}

// ---------------------------------------------------------------------------
extern "C" void kernel_launch(void* const* d_in, const int* in_sizes, int n_in,
                              void* d_out, int out_size, void* d_ws, size_t ws_size,
                              hipStream_t stream) {
  const float* x     = (const float*)d_in[0];   // [B,N,I]
  const int*   amask = (const int*)d_in[1];     // [B,N]
  const float* demb  = (const float*)d_in[2];   // [C,D,I]
  const int*   dmask = (const int*)d_in[3];     // [C,D]
  const float* Wq    = (const float*)d_in[4];
  const float* Wk    = (const float*)d_in[5];
  const float* Wv    = (const float*)d_in[6];
  const float* Wo    = (const float*)d_in[7];   // [1,I]
  const float* bo    = (const float*)d_in[8];   // [1]
  const float* lng   = (const float*)d_in[9];
  const float* lnb   = (const float*)d_in[10];

  char* ws = (char*)d_ws;
  // Region A (0 .. 134.2MB): conversion buffers -> P fp8 (attn) -> pv partials.
  const size_t OFF_QB  = 0;                                   // 25.2 MB
  const size_t OFF_XB  = OFF_QB + (size_t)MM * II * 2;        // 6.3 MB
  const size_t OFF_WQB = OFF_XB + (size_t)BB * NN * II * 2;   // 1.2 MB
  const size_t OFF_WKB = OFF_WQB + (size_t)II * II * 2;
  const size_t OFF_WVB = OFF_WKB + (size_t)II * II * 2;
  const size_t OFF_P   = 0;                                   // 67.1 MB (fp8)
  const size_t OFF_PL  = 0;                                   // 4 x 1.6 MB (dead P)
  // Region B (after worst-case old P extent, layout kept identical):
  const size_t OFF_QP = (size_t)BB * MM * NN * 2;             // 25.2 MB
  const size_t OFF_KP = OFF_QP + (size_t)MM * II * 2;         // 6.3 MB
  const size_t OFF_VT = OFF_KP + (size_t)BB * NN * II * 2;    // 6.3 MB
  const size_t OFF_LP = OFF_VT + (size_t)BB * II * NN * 2;    // 4.2 MB (16 partials)
  const size_t OFF_PP = OFF_LP + (size_t)BB * 16 * MM * 4;    // 2.1 MB
  const size_t OFF_IDX = OFF_PP + (size_t)BB * CC * NN * 2;   // 64 KB
  const size_t OFF_CS  = OFF_IDX + (size_t)MM * 4;            // 1 KB
  const size_t OFF_CNT = OFF_CS + (size_t)CC * 4;             // 1 KB
  const size_t OFF_MET = OFF_CNT + (size_t)CC * 4;            // 4 B

  unsigned short* Qb  = (unsigned short*)(ws + OFF_QB);
  unsigned short* xb  = (unsigned short*)(ws + OFF_XB);
  unsigned short* Wqb = (unsigned short*)(ws + OFF_WQB);
  unsigned short* Wkb = (unsigned short*)(ws + OFF_WKB);
  unsigned short* Wvb = (unsigned short*)(ws + OFF_WVB);
  unsigned char*  P   = (unsigned char*)(ws + OFF_P);
  float* pooled = (float*)(ws + OFF_PL);
  unsigned short* Qp  = (unsigned short*)(ws + OFF_QP);
  unsigned short* Kp  = (unsigned short*)(ws + OFF_KP);
  unsigned short* Vt  = (unsigned short*)(ws + OFF_VT);
  float* lpart = (float*)(ws + OFF_LP);
  unsigned short* pp = (unsigned short*)(ws + OFF_PP);
  int* idx    = (int*)(ws + OFF_IDX);
  int* cstart = (int*)(ws + OFF_CS);
  int* ccnt   = (int*)(ws + OFF_CNT);
  int* meta   = (int*)(ws + OFF_MET);

  cvt_scan_kernel<<<2048, 256, 0, stream>>>(demb, x, Wq, Wk, Wv, dmask,
                                            Qb, xb, Wqb, Wkb, Wvb,
                                            idx, cstart, ccnt, meta);

  proj3<<<192 * 6, 256, 0, stream>>>(Qb, xb, Wqb, Wkb, Wvb, Qp, Kp, Vt, idx, meta);

  attn_gemm1<<<dim3(NN / 128, BB, MM / 128), 256, 0, stream>>>(
      Qp, Kp, amask, meta, lpart, P);
  ppred_kernel<<<dim3(CC, BB, 2), 128, 0, stream>>>(P, lpart, cstart, ccnt, pp);

  pv_gemm<<<dim3((BB * CC) / 64, II / 64, 4), 256, 0, stream>>>(pp, Vt, pooled);
  ln_out_kernel<<<BB * CC, 256, 0, stream>>>(pooled, lng, lnb, Wo, bo, (float*)d_out);
}

// Round 14
// 146.582 us; speedup vs baseline: 1.2656x; 1.0139x over previous
//
#include <hip/hip_runtime.h>
#include <hip/hip_bf16.h>

#define BB 2
#define NN 2048
#define II 768
#define CC 256
#define DD 64
#define MM (CC * DD)   // 16384 q-rows (worst case)

typedef __attribute__((ext_vector_type(8))) short short8;
typedef __attribute__((ext_vector_type(4))) float f32x4;

static constexpr float SCALE = 0.036084391824351615f; // 1/sqrt(768)

__device__ __forceinline__ unsigned short f2bf(float f) {
  union { float f; unsigned int u; } v; v.f = f;
  unsigned int u = v.u;
  unsigned int r = u + 0x7fffu + ((u >> 16) & 1u);
  return (unsigned short)(r >> 16);
}
__device__ __forceinline__ float bf2f(unsigned short h) {
  union { unsigned int u; float f; } v; v.u = ((unsigned int)h) << 16;
  return v.f;
}

union U8 { unsigned short us[8]; uint4 v; };
struct US4 { unsigned short x, y, z, w; };

#define GLOAD_LDS16(gp, lp)                                                    \
  __builtin_amdgcn_global_load_lds(                                            \
      (const __attribute__((address_space(1))) unsigned int*)(gp),             \
      (__attribute__((address_space(3))) unsigned int*)(lp), 16, 0, 0)

// ---------------------------------------------------------------------------
// Fused f32->bf16 conversion (all blocks, grid-stride) + valid-row scan
// (last block only).  demb rows with dmask==0 skipped entirely.
// ---------------------------------------------------------------------------
__global__ __launch_bounds__(256)
void cvt_scan_kernel(const float* __restrict__ demb, const float* __restrict__ x,
                     const float* __restrict__ Wq, const float* __restrict__ Wk,
                     const float* __restrict__ Wv, const int* __restrict__ dmask,
                     unsigned short* __restrict__ Qb, unsigned short* __restrict__ xb,
                     unsigned short* __restrict__ Wqb, unsigned short* __restrict__ Wkb,
                     unsigned short* __restrict__ Wvb,
                     int* __restrict__ idx, int* __restrict__ cstart,
                     int* __restrict__ ccnt, int* __restrict__ meta)
{
  if (blockIdx.x == gridDim.x - 1) {
    const int c = threadIdx.x;
    int4 dmv[16];
    const int4* src = (const int4*)(dmask + c * 64);
    int cnt = 0;
    #pragma unroll
    for (int u = 0; u < 16; ++u) {
      dmv[u] = src[u];
      cnt += (dmv[u].x != 0) + (dmv[u].y != 0) + (dmv[u].z != 0) + (dmv[u].w != 0);
    }
    __shared__ int s[256];
    s[c] = cnt;
    __syncthreads();
    for (int off = 1; off < 256; off <<= 1) {
      int v = (c >= off) ? s[c - off] : 0;
      __syncthreads();
      s[c] += v;
      __syncthreads();
    }
    const int excl = s[c] - cnt;
    cstart[c] = excl;
    ccnt[c] = cnt;
    int j = excl;
    #pragma unroll
    for (int u = 0; u < 16; ++u) {
      if (dmv[u].x) idx[j++] = c * 64 + u * 4 + 0;
      if (dmv[u].y) idx[j++] = c * 64 + u * 4 + 1;
      if (dmv[u].z) idx[j++] = c * 64 + u * 4 + 2;
      if (dmv[u].w) idx[j++] = c * 64 + u * 4 + 3;
    }
    if (c == 255) {
      int mv = s[255];
      int mpad = (mv + 127) & ~127;
      for (int t = mv; t < mpad; ++t) idx[t] = 0;  // pad -> row 0 (valid)
      meta[0] = mpad;
    }
  }
  const int NF_DEMB = 3145728;          // elems/4
  const int NF_X    = 786432;
  const int NF_W    = 147456;
  const int NF_TOT  = NF_DEMB + NF_X + 3 * NF_W;
  for (int i = blockIdx.x * 256 + threadIdx.x; i < NF_TOT; i += gridDim.x * 256) {
    const float* src; unsigned short* dst; int off;
    if (i < NF_DEMB) {
      if (dmask[i / 192] == 0) continue;   // 192 float4-groups per row
      src = demb; dst = Qb; off = i;
    }
    else if (i < NF_DEMB + NF_X) { src = x; dst = xb; off = i - NF_DEMB; }
    else if (i < NF_DEMB + NF_X + NF_W) { src = Wq; dst = Wqb; off = i - NF_DEMB - NF_X; }
    else if (i < NF_DEMB + NF_X + 2 * NF_W) { src = Wk; dst = Wkb; off = i - NF_DEMB - NF_X - NF_W; }
    else { src = Wv; dst = Wvb; off = i - NF_DEMB - NF_X - 2 * NF_W; }
    float4 v = *(const float4*)(src + (size_t)off * 4);
    US4 o; o.x = f2bf(v.x); o.y = f2bf(v.y); o.z = f2bf(v.z); o.w = f2bf(v.w);
    *(US4*)(dst + (size_t)off * 4) = o;
  }
}

// ---------------------------------------------------------------------------
// All three projections in ONE dispatch (j-panel = T%6; t=T/6 selects
// Q(gathered, ghost-exit) / K / V).  128x128, BK=64, 4 waves,
// global_load_lds w16, XOR-swizzled source.
// V-mode stores: 4 consecutive-n bf16 packed into one 8B store.
// ---------------------------------------------------------------------------
__global__ __launch_bounds__(256, 2)
void proj3(const unsigned short* __restrict__ Qb,
           const unsigned short* __restrict__ xb,
           const unsigned short* __restrict__ Wqb,
           const unsigned short* __restrict__ Wkb,
           const unsigned short* __restrict__ Wvb,
           unsigned short* __restrict__ Qp,
           unsigned short* __restrict__ Kp,
           unsigned short* __restrict__ Vt,
           const int* __restrict__ gidx, const int* __restrict__ meta)
{
  const int T = blockIdx.x;
  const int j0 = (T % 6) * 128;
  const int t = T / 6;
  const int mode = (t < 128) ? 0 : ((t < 160) ? 1 : 2);
  const int m0 = (mode == 0 ? t : (mode == 1 ? t - 128 : t - 160)) * 128;
  if (mode == 0 && m0 >= meta[0]) return;
  const unsigned short* A = (mode == 0) ? Qb : xb;
  const unsigned short* W = (mode == 0) ? Wqb : (mode == 1 ? Wkb : Wvb);

  const int tid = threadIdx.x;
  const int lane = tid & 63, wv = tid >> 6;
  const int lrow = lane & 15, khi = lane >> 4;
  const int wr = wv >> 1, wc = wv & 1;

  __shared__ __align__(16) unsigned short smem[128 * 128];
  unsigned short* a_lds = smem;
  unsigned short* b_lds = smem + 128 * 64;

  int rowsrc[4];
  #pragma unroll
  for (int u = 0; u < 4; ++u) {
    int row = m0 + ((u * 256 + tid) >> 3);
    rowsrc[u] = (mode == 0) ? gidx[row] : row;
  }

  f32x4 acc[4][4] = {};

  for (int kc = 0; kc < 12; ++kc) {
    const int k0 = kc * 64;
    __syncthreads();
    #pragma unroll
    for (int u = 0; u < 4; ++u) {
      int idx = u * 256 + tid;
      int row = idx >> 3, g = idx & 7;
      int sg = g ^ (row & 7);
      GLOAD_LDS16(A + (size_t)rowsrc[u] * II + k0 + sg * 8, &a_lds[idx * 8]);
      GLOAD_LDS16(W + (size_t)(j0 + row) * II + k0 + sg * 8, &b_lds[idx * 8]);
    }
    __syncthreads();
    #pragma unroll
    for (int s = 0; s < 2; ++s) {
      short8 af[4], bf[4];
      #pragma unroll
      for (int m = 0; m < 4; ++m) {
        int ar = wr * 64 + m * 16 + lrow;
        int g = s * 4 + khi;
        af[m] = *(const short8*)&a_lds[(ar * 8 + (g ^ (ar & 7))) * 8];
      }
      #pragma unroll
      for (int f = 0; f < 4; ++f) {
        int br = wc * 64 + f * 16 + lrow;
        int g = s * 4 + khi;
        bf[f] = *(const short8*)&b_lds[(br * 8 + (g ^ (br & 7))) * 8];
      }
      #pragma unroll
      for (int m = 0; m < 4; ++m)
        #pragma unroll
        for (int f = 0; f < 4; ++f)
          acc[m][f] = __builtin_amdgcn_mfma_f32_16x16x32_bf16(af[m], bf[f], acc[m][f], 0, 0, 0);
    }
  }

  if (mode != 2) {
    unsigned short* out = (mode == 0) ? Qp : Kp;
    __syncthreads();   // repurpose smem as 128x128 bf16 C tile
    #pragma unroll
    for (int m = 0; m < 4; ++m)
      #pragma unroll
      for (int r = 0; r < 4; ++r) {
        const int row = wr * 64 + m * 16 + khi * 4 + r;
        const int s8 = (row & 7) << 3;
        #pragma unroll
        for (int f = 0; f < 4; ++f) {
          int col = wc * 64 + f * 16 + lrow;
          smem[row * 128 + (col ^ s8)] = f2bf(acc[m][f][r]);
        }
      }
    __syncthreads();
    #pragma unroll
    for (int u = 0; u < 8; ++u) {
      int idx = u * 256 + tid;
      int row = idx >> 4, q = idx & 15;
      int gcol = (q ^ (row & 7)) << 3;
      *(uint4*)(out + (size_t)(m0 + row) * II + j0 + gcol) =
          *(const uint4*)&smem[row * 128 + q * 8];
    }
  } else {
    // Vt[(b*II+col)*NN + n]: r=0..3 are consecutive n -> one 8B store each
    #pragma unroll
    for (int m = 0; m < 4; ++m)
      #pragma unroll
      for (int f = 0; f < 4; ++f) {
        int row = m0 + wr * 64 + m * 16 + khi * 4;     // +r, r consecutive
        int col = j0 + wc * 64 + f * 16 + lrow;
        int bb = row >> 11, n = row & (NN - 1);
        US4 o;
        o.x = f2bf(acc[m][f][0]); o.y = f2bf(acc[m][f][1]);
        o.z = f2bf(acc[m][f][2]); o.w = f2bf(acc[m][f][3]);
        *(US4*)(Vt + ((size_t)bb * II + col) * NN + n) = o;
      }
  }
}

// ---------------------------------------------------------------------------
// Attention score GEMM over COMPACT rows (proven structure: MfmaUtil 30%,
// 0 bank conflicts).  Grid (x=ny, y=b, z=mx).  128x128, BK=64, 4 waves,
// global_load_lds w16, XOR-swizzled.  Epilogue: P -> FP8 e4m3.
// LDS trimmed to exactly 32KB (red_lds aliases the dead upper half of smem
// during the epilogue) -> 5 blocks/CU residency WITHOUT touching
// launch_bounds (round-9 lesson: never constrain regalloc; VGPR stays 64).
// ---------------------------------------------------------------------------
__global__ __launch_bounds__(256, 4)
void attn_gemm1(const unsigned short* __restrict__ Qp,
                const unsigned short* __restrict__ Kp,
                const int* __restrict__ amask, const int* __restrict__ meta,
                float* __restrict__ lpart_out,
                unsigned char* __restrict__ P_out)
{
  const int m0 = blockIdx.z * 128;
  if (m0 >= meta[0]) return;
  const int ny = blockIdx.x;
  const int n0 = ny * 128;
  const int b  = blockIdx.y;
  const int tid = threadIdx.x;
  const int lane = tid & 63, wv = tid >> 6;
  const int lrow = lane & 15, khi = lane >> 4;
  const int wr = wv >> 1, wc = wv & 1;

  __shared__ __align__(16) unsigned short smem[128 * 128]; // 32 KB total LDS
  unsigned short* a_lds = smem;              // 128*64
  unsigned short* b_lds = smem + 128 * 64;   // 128*64
  // epilogue aliases: P fp8 tile = bytes [0,16384); red floats = [16384,17408)
  unsigned char* smemB  = (unsigned char*)smem;
  float* red_lds = (float*)(smemB + 16384);

  const unsigned short* Kb = Kp + (size_t)b * NN * II;

  f32x4 acc[4][4] = {};

  for (int kc = 0; kc < 12; ++kc) {
    const int k0 = kc * 64;
    __syncthreads();
    #pragma unroll
    for (int u = 0; u < 4; ++u) {
      int idx = u * 256 + tid;          // 1024 slots of 8 bf16 (16B)
      int row = idx >> 3, g = idx & 7;
      int sg = g ^ (row & 7);
      GLOAD_LDS16(Qp + (size_t)(m0 + row) * II + k0 + sg * 8, &a_lds[idx * 8]);
      GLOAD_LDS16(Kb + (size_t)(n0 + row) * II + k0 + sg * 8, &b_lds[idx * 8]);
    }
    __syncthreads();
    #pragma unroll
    for (int s = 0; s < 2; ++s) {
      short8 af[4], bf[4];
      #pragma unroll
      for (int m = 0; m < 4; ++m) {
        int ar = wr * 64 + m * 16 + lrow;
        int g = s * 4 + khi;
        af[m] = *(const short8*)&a_lds[(ar * 8 + (g ^ (ar & 7))) * 8];
      }
      #pragma unroll
      for (int f = 0; f < 4; ++f) {
        int br = wc * 64 + f * 16 + lrow;
        int g = s * 4 + khi;
        bf[f] = *(const short8*)&b_lds[(br * 8 + (g ^ (br & 7))) * 8];
      }
      #pragma unroll
      for (int m = 0; m < 4; ++m)
        #pragma unroll
        for (int f = 0; f < 4; ++f)
          acc[m][f] = __builtin_amdgcn_mfma_f32_16x16x32_bf16(af[m], bf[f], acc[m][f], 0, 0, 0);
    }
  }

  float msk[4];
  #pragma unroll
  for (int f = 0; f < 4; ++f)
    msk[f] = (amask[b * NN + n0 + wc * 64 + f * 16 + lrow] != 0) ? 1.0f : 0.0f;

  __syncthreads();   // done with a_lds/b_lds; repurpose smem (P fp8 + red)

  #pragma unroll
  for (int m = 0; m < 4; ++m) {
    #pragma unroll
    for (int r = 0; r < 4; ++r) {
      const int row = wr * 64 + m * 16 + khi * 4 + r;     // 0..127 local
      const int s8 = (row & 7) << 3;                       // 8-byte-group XOR
      float rs = 0.0f;
      #pragma unroll
      for (int f = 0; f < 4; ++f) {
        float pe = msk[f] * __expf(acc[m][f][r] * SCALE);
        rs += pe;
        int col = wc * 64 + f * 16 + lrow;                 // byte col 0..127
        smemB[row * 128 + (col ^ s8)] =
            (unsigned char)(__builtin_amdgcn_cvt_pk_fp8_f32(pe, pe, 0, 0) & 0xff);
      }
      rs += __shfl_xor(rs, 1); rs += __shfl_xor(rs, 2);
      rs += __shfl_xor(rs, 4); rs += __shfl_xor(rs, 8);
      if (lrow == 0) red_lds[row * 2 + wc] = rs;
    }
  }
  __syncthreads();
  if (tid < 128)
    lpart_out[((size_t)(b * 16 + ny) << 14) + m0 + tid] =
        red_lds[tid * 2] + red_lds[tid * 2 + 1];
  unsigned char* Pb = P_out + (size_t)b * MM * NN;
  #pragma unroll
  for (int u = 0; u < 8; ++u) {
    int idx = u * 256 + tid;            // 2048 uint2 slots (8 B each)
    int row = idx >> 4, q = idx & 15;
    int gcol = (q ^ (row & 7)) << 3;    // un-swizzled byte col group
    *(uint2*)(Pb + (size_t)(m0 + row) * NN + n0 + gcol) =
        *(const uint2*)&smemB[row * 128 + q * 8];
  }
}

// ---------------------------------------------------------------------------
// pp[b,c,n] = (1/cnt_c) * sum_{r in class c} P[b][r][n] / l_r  (P is fp8
// e4m3, HW-decoded).  l_r = sum of 16 partials.  Grid (CC, BB, 2).
// ---------------------------------------------------------------------------
__global__ __launch_bounds__(128)
void ppred_kernel(const unsigned char* __restrict__ P,
                  const float* __restrict__ lpart,
                  const int* __restrict__ cstart, const int* __restrict__ ccnt,
                  unsigned short* __restrict__ pp)
{
  const int c = blockIdx.x, b = blockIdx.y;
  const int nz = blockIdx.z * 1024;
  const int tid = threadIdx.x;
  const int cs = cstart[c], cnt = ccnt[c];
  __shared__ float wgt[64];
  if (tid < cnt) {
    float lv = 0.0f;
    #pragma unroll
    for (int nt = 0; nt < 16; ++nt)
      lv += lpart[(((size_t)(b * 16 + nt)) << 14) + cs + tid];
    wgt[tid] = 1.0f / lv;
  }
  __syncthreads();
  const float invd = 1.0f / (float)cnt;
  float acc[8] = {};
  const unsigned char* Pr = P + ((size_t)b * MM + cs) * NN + nz + tid * 8;
  #pragma unroll 4
  for (int d = 0; d < cnt; ++d) {
    uint2 v = *(const uint2*)(Pr + (size_t)d * NN);
    float w = wgt[d];
    acc[0] += w * __builtin_amdgcn_cvt_f32_fp8(v.x, 0);
    acc[1] += w * __builtin_amdgcn_cvt_f32_fp8(v.x, 1);
    acc[2] += w * __builtin_amdgcn_cvt_f32_fp8(v.x, 2);
    acc[3] += w * __builtin_amdgcn_cvt_f32_fp8(v.x, 3);
    acc[4] += w * __builtin_amdgcn_cvt_f32_fp8(v.y, 0);
    acc[5] += w * __builtin_amdgcn_cvt_f32_fp8(v.y, 1);
    acc[6] += w * __builtin_amdgcn_cvt_f32_fp8(v.y, 2);
    acc[7] += w * __builtin_amdgcn_cvt_f32_fp8(v.y, 3);
  }
  U8 o;
  #pragma unroll
  for (int e = 0; e < 8; ++e) o.us[e] = f2bf(acc[e] * invd);
  *(uint4*)(pp + ((size_t)(b * CC + c)) * NN + nz + tid * 8) = o.v;
}

// ---------------------------------------------------------------------------
// PV GEMM, K-SPLIT x4: pooled_z[mc][j] = sum_{n in quarter z} pp*Vt
// 384 blocks; 4 f32 partial buffers (summed in ln_out).
// ---------------------------------------------------------------------------
__global__ __launch_bounds__(256, 2)
void pv_gemm(const unsigned short* __restrict__ pp,
             const unsigned short* __restrict__ Vt,
             float* __restrict__ pooled)
{
  const int m0 = blockIdx.x * 64;
  const int j0 = blockIdx.y * 64;
  const int b  = m0 >> 8;
  const int z  = blockIdx.z;
  const int tid = threadIdx.x;
  const int lane = tid & 63, wv = tid >> 6;
  const int lrow = lane & 15, khi = lane >> 4;

  __shared__ __align__(16) unsigned short a_lds[64 * 128];
  __shared__ __align__(16) unsigned short b_lds[64 * 128];

  f32x4 acc[4] = {};

  for (int kc = z * 4; kc < z * 4 + 4; ++kc) {
    const int k0 = kc * 128;
    __syncthreads();
    #pragma unroll
    for (int u = 0; u < 4; ++u) {
      int idx = u * 256 + tid;
      int row = idx >> 4, g = idx & 15;
      int sg = g ^ (row & 7);
      GLOAD_LDS16(pp + (size_t)(m0 + row) * NN + k0 + sg * 8, &a_lds[idx * 8]);
      GLOAD_LDS16(Vt + ((size_t)b * II + j0 + row) * NN + k0 + sg * 8, &b_lds[idx * 8]);
    }
    __syncthreads();
    #pragma unroll
    for (int s = 0; s < 4; ++s) {
      int g = s * 4 + khi;
      int ar = 16 * wv + lrow;
      short8 af = *(const short8*)&a_lds[(ar * 16 + (g ^ (ar & 7))) * 8];
      #pragma unroll
      for (int f = 0; f < 4; ++f) {
        int br = f * 16 + lrow;
        short8 bfr = *(const short8*)&b_lds[(br * 16 + (g ^ (br & 7))) * 8];
        acc[f] = __builtin_amdgcn_mfma_f32_16x16x32_bf16(af, bfr, acc[f], 0, 0, 0);
      }
    }
  }
  float* out = pooled + (size_t)z * (BB * CC * II);
  #pragma unroll
  for (int f = 0; f < 4; ++f)
    #pragma unroll
    for (int r = 0; r < 4; ++r) {
      int row = m0 + 16 * wv + khi * 4 + r;
      int col = j0 + f * 16 + lrow;
      out[(size_t)row * II + col] = acc[f][r];
    }
}

// ---------------------------------------------------------------------------
// LayerNorm over i (summing 4 pv partials) + dot with Wo.
// ---------------------------------------------------------------------------
__global__ __launch_bounds__(256)
void ln_out_kernel(const float* __restrict__ pooled,
                   const float* __restrict__ g, const float* __restrict__ beta,
                   const float* __restrict__ Wo, const float* __restrict__ bo,
                   float* __restrict__ out)
{
  const int bc = blockIdx.x;
  const int tid = threadIdx.x;
  const int lane = tid & 63, wv = tid >> 6;
  const size_t PSZ = (size_t)BB * CC * II;
  const float* r0 = pooled + (size_t)bc * II;
  float x0 = r0[tid]       + r0[PSZ + tid]       + r0[2 * PSZ + tid]       + r0[3 * PSZ + tid];
  float x1 = r0[tid + 256] + r0[PSZ + tid + 256] + r0[2 * PSZ + tid + 256] + r0[3 * PSZ + tid + 256];
  float x2 = r0[tid + 512] + r0[PSZ + tid + 512] + r0[2 * PSZ + tid + 512] + r0[3 * PSZ + tid + 512];
  float s = x0 + x1 + x2;
  float sq = x0 * x0 + x1 * x1 + x2 * x2;
  #pragma unroll
  for (int m = 1; m < 64; m <<= 1) { s += __shfl_xor(s, m); sq += __shfl_xor(sq, m); }
  __shared__ float red[8];
  if (lane == 0) { red[wv] = s; red[4 + wv] = sq; }
  __syncthreads();
  s = red[0] + red[1] + red[2] + red[3];
  sq = red[4] + red[5] + red[6] + red[7];
  const float mu = s * (1.0f / 768.0f);
  const float var = sq * (1.0f / 768.0f) - mu * mu;
  const float rs = rsqrtf(var + 1e-5f);
  float dot = ((x0 - mu) * rs * g[tid] + beta[tid]) * Wo[tid]
            + ((x1 - mu) * rs * g[tid + 256] + beta[tid + 256]) * Wo[tid + 256]
            + ((x2 - mu) * rs * g[tid + 512] + beta[tid + 512]) * Wo[tid + 512];
  #pragma unroll
  for (int m = 1; m < 64; m <<= 1) dot += __shfl_xor(dot, m);
  __syncthreads();
  if (lane == 0) red[wv] = dot;
  __syncthreads();
  if (tid == 0) out[bc] = red[0] + red[1] + red[2] + red[3] + bo[0];
}

// ---------------------------------------------------------------------------
extern "C" void kernel_launch(void* const* d_in, const int* in_sizes, int n_in,
                              void* d_out, int out_size, void* d_ws, size_t ws_size,
                              hipStream_t stream) {
  const float* x     = (const float*)d_in[0];   // [B,N,I]
  const int*   amask = (const int*)d_in[1];     // [B,N]
  const float* demb  = (const float*)d_in[2];   // [C,D,I]
  const int*   dmask = (const int*)d_in[3];     // [C,D]
  const float* Wq    = (const float*)d_in[4];
  const float* Wk    = (const float*)d_in[5];
  const float* Wv    = (const float*)d_in[6];
  const float* Wo    = (const float*)d_in[7];   // [1,I]
  const float* bo    = (const float*)d_in[8];   // [1]
  const float* lng   = (const float*)d_in[9];
  const float* lnb   = (const float*)d_in[10];

  char* ws = (char*)d_ws;
  // Region A (0 .. 134.2MB): conversion buffers -> P fp8 (attn) -> pv partials.
  const size_t OFF_QB  = 0;                                   // 25.2 MB
  const size_t OFF_XB  = OFF_QB + (size_t)MM * II * 2;        // 6.3 MB
  const size_t OFF_WQB = OFF_XB + (size_t)BB * NN * II * 2;   // 1.2 MB
  const size_t OFF_WKB = OFF_WQB + (size_t)II * II * 2;
  const size_t OFF_WVB = OFF_WKB + (size_t)II * II * 2;
  const size_t OFF_P   = 0;                                   // 67.1 MB (fp8)
  const size_t OFF_PL  = 0;                                   // 4 x 1.6 MB (dead P)
  // Region B (after worst-case old P extent, layout kept identical):
  const size_t OFF_QP = (size_t)BB * MM * NN * 2;             // 25.2 MB
  const size_t OFF_KP = OFF_QP + (size_t)MM * II * 2;         // 6.3 MB
  const size_t OFF_VT = OFF_KP + (size_t)BB * NN * II * 2;    // 6.3 MB
  const size_t OFF_LP = OFF_VT + (size_t)BB * II * NN * 2;    // 4.2 MB (16 partials)
  const size_t OFF_PP = OFF_LP + (size_t)BB * 16 * MM * 4;    // 2.1 MB
  const size_t OFF_IDX = OFF_PP + (size_t)BB * CC * NN * 2;   // 64 KB
  const size_t OFF_CS  = OFF_IDX + (size_t)MM * 4;            // 1 KB
  const size_t OFF_CNT = OFF_CS + (size_t)CC * 4;             // 1 KB
  const size_t OFF_MET = OFF_CNT + (size_t)CC * 4;            // 4 B

  unsigned short* Qb  = (unsigned short*)(ws + OFF_QB);
  unsigned short* xb  = (unsigned short*)(ws + OFF_XB);
  unsigned short* Wqb = (unsigned short*)(ws + OFF_WQB);
  unsigned short* Wkb = (unsigned short*)(ws + OFF_WKB);
  unsigned short* Wvb = (unsigned short*)(ws + OFF_WVB);
  unsigned char*  P   = (unsigned char*)(ws + OFF_P);
  float* pooled = (float*)(ws + OFF_PL);
  unsigned short* Qp  = (unsigned short*)(ws + OFF_QP);
  unsigned short* Kp  = (unsigned short*)(ws + OFF_KP);
  unsigned short* Vt  = (unsigned short*)(ws + OFF_VT);
  float* lpart = (float*)(ws + OFF_LP);
  unsigned short* pp = (unsigned short*)(ws + OFF_PP);
  int* idx    = (int*)(ws + OFF_IDX);
  int* cstart = (int*)(ws + OFF_CS);
  int* ccnt   = (int*)(ws + OFF_CNT);
  int* meta   = (int*)(ws + OFF_MET);

  cvt_scan_kernel<<<2048, 256, 0, stream>>>(demb, x, Wq, Wk, Wv, dmask,
                                            Qb, xb, Wqb, Wkb, Wvb,
                                            idx, cstart, ccnt, meta);

  proj3<<<192 * 6, 256, 0, stream>>>(Qb, xb, Wqb, Wkb, Wvb, Qp, Kp, Vt, idx, meta);

  attn_gemm1<<<dim3(NN / 128, BB, MM / 128), 256, 0, stream>>>(
      Qp, Kp, amask, meta, lpart, P);
  ppred_kernel<<<dim3(CC, BB, 2), 128, 0, stream>>>(P, lpart, cstart, ccnt, pp);

  pv_gemm<<<dim3((BB * CC) / 64, II / 64, 4), 256, 0, stream>>>(pp, Vt, pooled);
  ln_out_kernel<<<BB * CC, 256, 0, stream>>>(pooled, lng, lnb, Wo, bo, (float*)d_out);
}